// Round 6
// baseline (598.379 us; speedup 1.0000x reference)
//
#include <hip/hip_runtime.h>
#include <math.h>

#define N_NODES 100000
#define N_EDGES 400000
#define HID 128
#define HEADS 4
#define OUT_C 64
#define HD 256   // HEADS*OUT_C
#define SCAN_CHUNK 1024
#define NB_SCAN ((N_NODES + SCAN_CHUNK - 1) / SCAN_CHUNK)   // 98
#define PSLAB 2576   // attn_pd slab region stride (ushorts; 64*40 + 16 pad)

typedef __attribute__((ext_vector_type(8))) short bf16x8;   // 8 bf16 = 4 VGPRs
typedef __attribute__((ext_vector_type(4))) float f32x4;

// fp32 -> bf16 round-to-nearest-even
__device__ __forceinline__ unsigned short fbf(float f) {
    unsigned u = __float_as_uint(f);
    unsigned r = (u + 0x7fffu + ((u >> 16) & 1u)) >> 16;
    return (unsigned short)r;
}
__device__ __forceinline__ float bf2f(unsigned short u) {
    return __uint_as_float(((unsigned)u) << 16);
}

// async global->LDS, 16B per lane; LDS dest = wave-uniform base + lane*16
__device__ __forceinline__ void gl_lds16(const void* g, void* l) {
    __builtin_amdgcn_global_load_lds(
        (const __attribute__((address_space(1))) unsigned int*)g,
        (__attribute__((address_space(3))) unsigned int*)l,
        16, 0, 0);
}

// ---------- CSR build: degree count ----------
__global__ __launch_bounds__(256) void k_deg(const int* __restrict__ ei,
                                             int* __restrict__ deg) {
    int e = blockIdx.x * 256 + threadIdx.x;
    if (e < N_EDGES) atomicAdd(&deg[ei[N_EDGES + e]], 1);
}

// ---------- scan 1 ----------
__global__ __launch_bounds__(256) void k_scan1(const int* __restrict__ deg,
                                               int* __restrict__ rp,
                                               int* __restrict__ bsum) {
    __shared__ int ts[256];
    int b = blockIdx.x, t = threadIdx.x;
    int base = b * SCAN_CHUNK + t * 4;
    int vv[4];
    int s = 0;
#pragma unroll
    for (int i = 0; i < 4; ++i) {
        int d = (base + i < N_NODES) ? deg[base + i] : 0;
        vv[i] = s;
        s += d;
    }
    ts[t] = s;
    __syncthreads();
    for (int off = 1; off < 256; off <<= 1) {
        int x = (t >= off) ? ts[t - off] : 0;
        __syncthreads();
        ts[t] += x;
        __syncthreads();
    }
    int ex = ts[t] - s;
#pragma unroll
    for (int i = 0; i < 4; ++i)
        if (base + i < N_NODES) rp[base + i] = ex + vv[i];
    if (t == 255) bsum[b] = ts[255];
}

// ---------- scan 2 ----------
__global__ __launch_bounds__(256) void k_scan2(int* __restrict__ bsum) {
    __shared__ int ts[256];
    int t = threadIdx.x;
    int v = (t < NB_SCAN) ? bsum[t] : 0;
    ts[t] = v;
    __syncthreads();
    for (int off = 1; off < 256; off <<= 1) {
        int x = (t >= off) ? ts[t - off] : 0;
        __syncthreads();
        ts[t] += x;
        __syncthreads();
    }
    if (t < NB_SCAN) bsum[t] = ts[t] - v;
}

// ---------- bucket: fill csr_src / csr_dst / csr_eid (rp finalized inline via bsum) ----------
__global__ __launch_bounds__(256) void k_bucket(const int* __restrict__ ei,
                                                const int* __restrict__ rp,
                                                const int* __restrict__ bsum,
                                                int* __restrict__ cursor,
                                                int* __restrict__ csr_src,
                                                int* __restrict__ csr_dst,
                                                int* __restrict__ csr_eid) {
    int e = blockIdx.x * 256 + threadIdx.x;
    if (e >= N_EDGES) return;
    int src = ei[e];
    int d   = ei[N_EDGES + e];
    int idx = atomicAdd(&cursor[d], 1);
    int s   = rp[d] + bsum[d >> 10] + idx;
    csr_src[s] = src;
    csr_dst[s] = d;
    csr_eid[s] = e;
}

// ---------- merged weight packing ----------
__global__ __launch_bounds__(256) void pack_all(
    const float* __restrict__ Wq, const float* __restrict__ Wk,
    const float* __restrict__ Wv, const float* __restrict__ Ws,
    const float* __restrict__ W1, const float* __restrict__ W2,
    unsigned short* __restrict__ Wp, unsigned short* __restrict__ Wcp,
    unsigned short* __restrict__ W2p) {
    int i = blockIdx.x * 256 + threadIdx.x;   // 25600 total
    int lane = i & 63;
    int q = lane >> 4, c = lane & 15;
    if (i < 16384) {
        int nt = (i >> 6) & 15, kt = (i >> 10) & 3, z = i >> 12;
        const float* W = (z == 0) ? Wq : (z == 1) ? Wk : (z == 2) ? Wv : Ws;
#pragma unroll
        for (int j = 0; j < 8; ++j)
            Wp[i * 8 + j] = fbf(W[(kt * 32 + q * 8 + j) * HD + nt * 16 + c]);
    } else if (i < 24576) {
        int ii = i - 16384;
        int nt = (ii >> 6) & 15, kt = ii >> 10;
        int n = nt * 16 + c;
#pragma unroll
        for (int j = 0; j < 8; ++j) {
            int k = kt * 32 + q * 8 + j;
            float v = (n < 128) ? W1[k * 128 + n] : W1[(k + 256) * 128 + (n - 128)];
            Wcp[ii * 8 + j] = fbf(v);
        }
    } else if (i < 25600) {
        int ii = i - 24576;
        int nt = (ii >> 6) & 3, kt = ii >> 8;
#pragma unroll
        for (int j = 0; j < 8; ++j)
            W2p[ii * 8 + j] = fbf(W2[(kt * 32 + q * 8 + j) * 64 + nt * 16 + c]);
    }
}

// ---------- K_pre: H = bf16(x + mem), one streaming pass ----------
__global__ __launch_bounds__(256) void k_pre(const float* __restrict__ x,
                                             const float* __restrict__ mem,
                                             unsigned short* __restrict__ H) {
    int idx = blockIdx.x * 256 + threadIdx.x;      // chunk of 8 elems
    if (idx >= N_NODES * HID / 8) return;          // 1,600,000 chunks
    const float4* x4 = (const float4*)x;
    const float4* m4 = (const float4*)mem;
    float4 a0 = x4[(size_t)idx * 2],     a1 = x4[(size_t)idx * 2 + 1];
    float4 b0 = m4[(size_t)idx * 2],     b1 = m4[(size_t)idx * 2 + 1];
    bf16x8 hv;
    hv[0] = (short)fbf(a0.x + b0.x); hv[1] = (short)fbf(a0.y + b0.y);
    hv[2] = (short)fbf(a0.z + b0.z); hv[3] = (short)fbf(a0.w + b0.w);
    hv[4] = (short)fbf(a1.x + b1.x); hv[5] = (short)fbf(a1.y + b1.y);
    hv[6] = (short)fbf(a1.z + b1.z); hv[7] = (short)fbf(a1.w + b1.w);
    *(bf16x8*)&H[(size_t)idx * 8] = hv;
}

// ---------- shared stage helper: H tile 64x128 bf16 into As (XOR-pre-swizzled src) ----------
__device__ __forceinline__ void stage_h(const unsigned short* __restrict__ H,
                                        short* As, int m0, int w, int l) {
#pragma unroll
    for (int i = 0; i < 2; ++i) {
        int rbase = w * 8 + i * 4;
        int r  = rbase + (l >> 4);
        int gr = m0 + r; if (gr >= N_NODES) gr = N_NODES - 1;   // clamp; stores guarded
        int ks = (l & 15) ^ (r & 7);
        gl_lds16(&H[(size_t)gr * HID + ks * 8], &As[rbase * 128]);
    }
}

// ---------- K1a: Q and S projections — operand-SWAPPED MFMA (O^T = W^T H^T) ----------
// mfma(A=W-frag, B=H-frag): thread holds out-cols (w*32+mt*16+q*4 .. +4) of node
// (nt*16+c) -> direct ushort4 global stores, no transpose slab, no epilogue barrier.
__global__ __launch_bounds__(512, 6) void gemm_qs(
    const unsigned short* __restrict__ H,
    const unsigned short* __restrict__ Wp,
    const float* __restrict__ bq, const float* __restrict__ bs,
    unsigned short* __restrict__ Q, unsigned short* __restrict__ S)
{
    __shared__ __align__(16) short As[64 * 128];   // 16 KB only

    const int t = threadIdx.x;
    const int w = t >> 6, l = t & 63;
    const int q = l >> 4, c = l & 15;
    const int m0 = blockIdx.x * 64;

    stage_h(H, As, m0, w, l);
    __syncthreads();

#pragma unroll
    for (int zz = 0; zz < 2; ++zz) {
        const int z = (zz == 0) ? 0 : 3;
        const float* bz = (zz == 0) ? bq : bs;
        unsigned short* Oz = (zz == 0) ? Q : S;

        f32x4 acc[2][4];
#pragma unroll
        for (int mt = 0; mt < 2; ++mt)
#pragma unroll
            for (int nt = 0; nt < 4; ++nt) acc[mt][nt] = (f32x4){0.f, 0.f, 0.f, 0.f};

#pragma unroll
        for (int kt = 0; kt < 4; ++kt) {
            bf16x8 hf[4];
#pragma unroll
            for (int nt = 0; nt < 4; ++nt) {
                int row  = nt * 16 + c;
                int slot = (kt * 4 + q) ^ (row & 7);
                hf[nt] = *(const bf16x8*)&As[row * 128 + slot * 8];
            }
#pragma unroll
            for (int mt = 0; mt < 2; ++mt) {
                bf16x8 wf = *(const bf16x8*)&Wp[(size_t)(((z * 4 + kt) * 16 + w * 2 + mt) * 64 + l) * 8];
#pragma unroll
                for (int nt = 0; nt < 4; ++nt)
                    acc[mt][nt] = __builtin_amdgcn_mfma_f32_16x16x32_bf16(wf, hf[nt], acc[mt][nt], 0, 0, 0);
            }
        }

#pragma unroll
        for (int mt = 0; mt < 2; ++mt) {
            float4 bb = *(const float4*)&bz[w * 32 + mt * 16 + q * 4];
#pragma unroll
            for (int nt = 0; nt < 4; ++nt) {
                int node = m0 + nt * 16 + c;
                if (node < N_NODES) {
                    ushort4 ov = make_ushort4(fbf(acc[mt][nt][0] + bb.x),
                                              fbf(acc[mt][nt][1] + bb.y),
                                              fbf(acc[mt][nt][2] + bb.z),
                                              fbf(acc[mt][nt][3] + bb.w));
                    *(ushort4*)&Oz[(size_t)node * HD + w * 32 + mt * 16 + q * 4] = ov;
                }
            }
        }
    }
}

// ---------- K1b: K and V projections — swapped MFMA + in-register KV merge ----------
// Same thread holds cols q*4..+4 of K (pass 1, compressed to ushort4) and V
// (pass 2) for node nt*16+c -> ONE full 16 B lane-interleaved KV store. No slab,
// no write-amp possible, LDS = 16 KB.
__global__ __launch_bounds__(512, 6) void gemm_kv(
    const unsigned short* __restrict__ H,
    const unsigned short* __restrict__ Wp,
    const float* __restrict__ bk, const float* __restrict__ bv,
    unsigned short* __restrict__ KV)
{
    __shared__ __align__(16) short As[64 * 128];   // 16 KB only

    const int t = threadIdx.x;
    const int w = t >> 6, l = t & 63;
    const int q = l >> 4, c = l & 15;
    const int m0 = blockIdx.x * 64;

    stage_h(H, As, m0, w, l);
    __syncthreads();

    f32x4 acc[2][4];
    ushort4 kf[2][4];

    // ---- K pass (z=1) ----
#pragma unroll
    for (int mt = 0; mt < 2; ++mt)
#pragma unroll
        for (int nt = 0; nt < 4; ++nt) acc[mt][nt] = (f32x4){0.f, 0.f, 0.f, 0.f};
#pragma unroll
    for (int kt = 0; kt < 4; ++kt) {
        bf16x8 hf[4];
#pragma unroll
        for (int nt = 0; nt < 4; ++nt) {
            int row  = nt * 16 + c;
            int slot = (kt * 4 + q) ^ (row & 7);
            hf[nt] = *(const bf16x8*)&As[row * 128 + slot * 8];
        }
#pragma unroll
        for (int mt = 0; mt < 2; ++mt) {
            bf16x8 wf = *(const bf16x8*)&Wp[(size_t)(((1 * 4 + kt) * 16 + w * 2 + mt) * 64 + l) * 8];
#pragma unroll
            for (int nt = 0; nt < 4; ++nt)
                acc[mt][nt] = __builtin_amdgcn_mfma_f32_16x16x32_bf16(wf, hf[nt], acc[mt][nt], 0, 0, 0);
        }
    }
#pragma unroll
    for (int mt = 0; mt < 2; ++mt) {
        float4 bb = *(const float4*)&bk[w * 32 + mt * 16 + q * 4];
#pragma unroll
        for (int nt = 0; nt < 4; ++nt)
            kf[mt][nt] = make_ushort4(fbf(acc[mt][nt][0] + bb.x),
                                      fbf(acc[mt][nt][1] + bb.y),
                                      fbf(acc[mt][nt][2] + bb.z),
                                      fbf(acc[mt][nt][3] + bb.w));
    }

    // ---- V pass (z=2), acc reused ----
#pragma unroll
    for (int mt = 0; mt < 2; ++mt)
#pragma unroll
        for (int nt = 0; nt < 4; ++nt) acc[mt][nt] = (f32x4){0.f, 0.f, 0.f, 0.f};
#pragma unroll
    for (int kt = 0; kt < 4; ++kt) {
        bf16x8 hf[4];
#pragma unroll
        for (int nt = 0; nt < 4; ++nt) {
            int row  = nt * 16 + c;
            int slot = (kt * 4 + q) ^ (row & 7);
            hf[nt] = *(const bf16x8*)&As[row * 128 + slot * 8];
        }
#pragma unroll
        for (int mt = 0; mt < 2; ++mt) {
            bf16x8 wf = *(const bf16x8*)&Wp[(size_t)(((2 * 4 + kt) * 16 + w * 2 + mt) * 64 + l) * 8];
#pragma unroll
            for (int nt = 0; nt < 4; ++nt)
                acc[mt][nt] = __builtin_amdgcn_mfma_f32_16x16x32_bf16(wf, hf[nt], acc[mt][nt], 0, 0, 0);
        }
    }

    // ---- merged store: chunk ch = w*8 + mt*4 + q holds cols ch*4..+4 ----
#pragma unroll
    for (int mt = 0; mt < 2; ++mt) {
        float4 bb = *(const float4*)&bv[w * 32 + mt * 16 + q * 4];
#pragma unroll
        for (int nt = 0; nt < 4; ++nt) {
            int node = m0 + nt * 16 + c;
            if (node < N_NODES) {
                bf16x8 ov;
                ov[0] = (short)kf[mt][nt].x; ov[1] = (short)kf[mt][nt].y;
                ov[2] = (short)kf[mt][nt].z; ov[3] = (short)kf[mt][nt].w;
                ov[4] = (short)fbf(acc[mt][nt][0] + bb.x);
                ov[5] = (short)fbf(acc[mt][nt][1] + bb.y);
                ov[6] = (short)fbf(acc[mt][nt][2] + bb.z);
                ov[7] = (short)fbf(acc[mt][nt][3] + bb.w);
                *(bf16x8*)&KV[(size_t)node * 512 + (w * 8 + mt * 4 + q) * 8] = ov;
            }
        }
    }
}

// ---------- K2: fused attention + PD GEMM ----------
// 512 threads = 8 waves; LDS = exactly 32 KB -> 4 blocks/CU (32 waves, 100%).
// Attention writes the out-tile pd-swizzled into As; PD GEMM consumes it; the
// transpose slab runs in TWO rounds (waves 0-3's col-half, then 4-7's) so the
// 20.6 KB slab fully aliases the dead As.
__global__ __launch_bounds__(512, 8) void attn_pd(
    const int* __restrict__ rp, const int* __restrict__ bsum,
    const int* __restrict__ deg, const int* __restrict__ csr_src,
    const unsigned short* __restrict__ Q, const unsigned short* __restrict__ KV,
    const unsigned short* __restrict__ S,
    const unsigned short* __restrict__ Wcp,
    unsigned short* __restrict__ PD)
{
    __shared__ __align__(16) short sh[64 * 256];   // 32768 B: As, slab aliases after GEMM
    short* As = sh;

    const int t = threadIdx.x;
    const int w = t >> 6, l = t & 63;
    const int q = l >> 4, c = l & 15;
    const int m0 = blockIdx.x * 64;

    // node metadata for this wave's 8 nodes, gathered wave-wide once
    int meta = 0;
    {
        int nn = m0 + w * 8 + (l & 7);
        if (nn < N_NODES) {
            if (l < 8)       meta = rp[nn] + bsum[nn >> 10];
            else if (l < 16) meta = deg[nn];
        }
    }

    // ---- attention phase: wave w -> rows w*8 .. w*8+8 ----
    for (int i = 0; i < 8; ++i) {
        int row  = w * 8 + i;
        int node = m0 + row;
        if (node < N_NODES) {
            int start = __shfl(meta, i);
            int cnt   = __shfl(meta, 8 + i);

            float q0, q1, q2, q3;   // pre-scaled by 1/sqrt(64)
            ushort4 su;
            {
                ushort4 u = *(const ushort4*)&Q[(size_t)node * HD + l * 4];
                su = *(const ushort4*)&S[(size_t)node * HD + l * 4];   // hoisted
                q0 = bf2f(u.x) * 0.125f; q1 = bf2f(u.y) * 0.125f;
                q2 = bf2f(u.z) * 0.125f; q3 = bf2f(u.w) * 0.125f;
            }

            float d = 0.f;
            float a0 = 0.f, a1 = 0.f, a2 = 0.f, a3 = 0.f;

            int i2 = 0;
            for (; i2 + 4 <= cnt; i2 += 4) {
                int s0 = csr_src[start + i2];
                int s1 = csr_src[start + i2 + 1];
                int s2 = csr_src[start + i2 + 2];
                int s3 = csr_src[start + i2 + 3];
                bf16x8 k0 = *(const bf16x8*)&KV[(size_t)s0 * 512 + l * 8];
                bf16x8 k1 = *(const bf16x8*)&KV[(size_t)s1 * 512 + l * 8];
                bf16x8 k2 = *(const bf16x8*)&KV[(size_t)s2 * 512 + l * 8];
                bf16x8 k3 = *(const bf16x8*)&KV[(size_t)s3 * 512 + l * 8];
                float sA = q0 * bf2f((unsigned short)k0[0]) + q1 * bf2f((unsigned short)k0[1])
                         + q2 * bf2f((unsigned short)k0[2]) + q3 * bf2f((unsigned short)k0[3]);
                float sB = q0 * bf2f((unsigned short)k1[0]) + q1 * bf2f((unsigned short)k1[1])
                         + q2 * bf2f((unsigned short)k1[2]) + q3 * bf2f((unsigned short)k1[3]);
                float sC = q0 * bf2f((unsigned short)k2[0]) + q1 * bf2f((unsigned short)k2[1])
                         + q2 * bf2f((unsigned short)k2[2]) + q3 * bf2f((unsigned short)k2[3]);
                float sD = q0 * bf2f((unsigned short)k3[0]) + q1 * bf2f((unsigned short)k3[1])
                         + q2 * bf2f((unsigned short)k3[2]) + q3 * bf2f((unsigned short)k3[3]);
                sA += __shfl_xor(sA, 1); sB += __shfl_xor(sB, 1);
                sC += __shfl_xor(sC, 1); sD += __shfl_xor(sD, 1);
                sA += __shfl_xor(sA, 2); sB += __shfl_xor(sB, 2);
                sC += __shfl_xor(sC, 2); sD += __shfl_xor(sD, 2);
                sA += __shfl_xor(sA, 4); sB += __shfl_xor(sB, 4);
                sC += __shfl_xor(sC, 4); sD += __shfl_xor(sD, 4);
                sA += __shfl_xor(sA, 8); sB += __shfl_xor(sB, 8);
                sC += __shfl_xor(sC, 8); sD += __shfl_xor(sD, 8);
                float eA = __expf(sA), eB = __expf(sB), eC = __expf(sC), eD = __expf(sD);
                d += (eA + eB) + (eC + eD);
                a0 += eA * bf2f((unsigned short)k0[4]) + eB * bf2f((unsigned short)k1[4])
                    + eC * bf2f((unsigned short)k2[4]) + eD * bf2f((unsigned short)k3[4]);
                a1 += eA * bf2f((unsigned short)k0[5]) + eB * bf2f((unsigned short)k1[5])
                    + eC * bf2f((unsigned short)k2[5]) + eD * bf2f((unsigned short)k3[5]);
                a2 += eA * bf2f((unsigned short)k0[6]) + eB * bf2f((unsigned short)k1[6])
                    + eC * bf2f((unsigned short)k2[6]) + eD * bf2f((unsigned short)k3[6]);
                a3 += eA * bf2f((unsigned short)k0[7]) + eB * bf2f((unsigned short)k1[7])
                    + eC * bf2f((unsigned short)k2[7]) + eD * bf2f((unsigned short)k3[7]);
            }
            if (i2 + 2 <= cnt) {
                int s0 = csr_src[start + i2];
                int s1 = csr_src[start + i2 + 1];
                bf16x8 k0 = *(const bf16x8*)&KV[(size_t)s0 * 512 + l * 8];
                bf16x8 k1 = *(const bf16x8*)&KV[(size_t)s1 * 512 + l * 8];
                float sA = q0 * bf2f((unsigned short)k0[0]) + q1 * bf2f((unsigned short)k0[1])
                         + q2 * bf2f((unsigned short)k0[2]) + q3 * bf2f((unsigned short)k0[3]);
                float sB = q0 * bf2f((unsigned short)k1[0]) + q1 * bf2f((unsigned short)k1[1])
                         + q2 * bf2f((unsigned short)k1[2]) + q3 * bf2f((unsigned short)k1[3]);
                sA += __shfl_xor(sA, 1); sB += __shfl_xor(sB, 1);
                sA += __shfl_xor(sA, 2); sB += __shfl_xor(sB, 2);
                sA += __shfl_xor(sA, 4); sB += __shfl_xor(sB, 4);
                sA += __shfl_xor(sA, 8); sB += __shfl_xor(sB, 8);
                float eA = __expf(sA), eB = __expf(sB);
                d += eA + eB;
                a0 += eA * bf2f((unsigned short)k0[4]) + eB * bf2f((unsigned short)k1[4]);
                a1 += eA * bf2f((unsigned short)k0[5]) + eB * bf2f((unsigned short)k1[5]);
                a2 += eA * bf2f((unsigned short)k0[6]) + eB * bf2f((unsigned short)k1[6]);
                a3 += eA * bf2f((unsigned short)k0[7]) + eB * bf2f((unsigned short)k1[7]);
                i2 += 2;
            }
            if (i2 < cnt) {
                int s0 = csr_src[start + i2];
                bf16x8 k0 = *(const bf16x8*)&KV[(size_t)s0 * 512 + l * 8];
                float sA = q0 * bf2f((unsigned short)k0[0]) + q1 * bf2f((unsigned short)k0[1])
                         + q2 * bf2f((unsigned short)k0[2]) + q3 * bf2f((unsigned short)k0[3]);
                sA += __shfl_xor(sA, 1);
                sA += __shfl_xor(sA, 2);
                sA += __shfl_xor(sA, 4);
                sA += __shfl_xor(sA, 8);
                float eA = __expf(sA);
                d += eA;
                a0 += eA * bf2f((unsigned short)k0[4]);
                a1 += eA * bf2f((unsigned short)k0[5]);
                a2 += eA * bf2f((unsigned short)k0[6]);
                a3 += eA * bf2f((unsigned short)k0[7]);
            }

            float inv = 1.f / (d + 1e-16f);
            ushort4 ov = make_ushort4(fbf(bf2f(su.x) + a0 * inv),
                                      fbf(bf2f(su.y) + a1 * inv),
                                      fbf(bf2f(su.z) + a2 * inv),
                                      fbf(bf2f(su.w) + a3 * inv));
            // write into PD A-tile, pd-swizzled: logical 16B-chunk lc=l>>1 of row
            // stored at physical chunk lc^(row&7), half (l&1)
            *(ushort4*)&As[row * 256 + (((l >> 1) ^ (row & 7)) << 3) + ((l & 1) << 2)] = ov;
        }
    }
    __syncthreads();   // out-tile complete

    // ---- PD GEMM phase: 8 waves x 2 N-tiles, K=256 ----
    f32x4 acc[4][2];
#pragma unroll
    for (int mt = 0; mt < 4; ++mt)
#pragma unroll
        for (int nt = 0; nt < 2; ++nt) acc[mt][nt] = (f32x4){0.f, 0.f, 0.f, 0.f};

#pragma unroll
    for (int kt = 0; kt < 8; ++kt) {
        bf16x8 af[4];
#pragma unroll
        for (int mt = 0; mt < 4; ++mt) {
            int row  = mt * 16 + c;
            int slot = (kt * 4 + q) ^ (row & 7);
            af[mt] = *(const bf16x8*)&As[row * 256 + slot * 8];
        }
#pragma unroll
        for (int nt = 0; nt < 2; ++nt) {
            int ntg = w * 2 + nt;
            bf16x8 bv8 = *(const bf16x8*)&Wcp[(size_t)((kt * 16 + ntg) * 64 + l) * 8];
#pragma unroll
            for (int mt = 0; mt < 4; ++mt)
                acc[mt][nt] = __builtin_amdgcn_mfma_f32_16x16x32_bf16(af[mt], bv8, acc[mt][nt], 0, 0, 0);
        }
    }
    __syncthreads();   // all As reads done; slab regions alias As

    // ---- two-round transpose epilogue: half h stores cols h*128..h*128+128 ----
#pragma unroll
    for (int h = 0; h < 2; ++h) {
        if ((w >> 2) == h) {
            short* slab = &sh[(w & 3) * PSLAB];   // region holds cols h*128+(w&3)*32 ..+32
#pragma unroll
            for (int nt = 0; nt < 2; ++nt)
#pragma unroll
                for (int mt = 0; mt < 4; ++mt)
#pragma unroll
                    for (int r = 0; r < 4; ++r)
                        slab[(mt * 16 + q * 4 + r) * 40 + nt * 16 + c] =
                            (short)fbf(acc[mt][nt][r]);
        }
        __syncthreads();
        {
            int cl   = l & 15;                       // col-chunk within this half
            int rsub = l >> 4;                       // 0..3
            const short* sb = &sh[(cl >> 2) * PSLAB + (cl & 3) * 8];
#pragma unroll
            for (int i = 0; i < 2; ++i) {
                int row = w * 8 + i * 4 + rsub;
                int gr  = m0 + row;
                if (gr < N_NODES)
                    *(bf16x8*)&PD[(size_t)gr * HD + (h * 16 + cl) * 8] =
                        *(const bf16x8*)&sb[row * 40];
            }
        }
        __syncthreads();   // before next half reuses the same slab regions
    }
}

// ---------- K5: light edge MLP — h1 = relu(P[src]+D[dst]+b1); layer2 MFMA; layer3 ----------
__global__ __launch_bounds__(256) void edge_mlp_pd(
    const int* __restrict__ csr_src, const int* __restrict__ csr_dst,
    const int* __restrict__ csr_eid,
    const unsigned short* __restrict__ PD,
    const float* __restrict__ b1,
    const unsigned short* __restrict__ W2p, const float* __restrict__ b2,
    const float* __restrict__ W3, const float* __restrict__ b3,
    float* __restrict__ rating)
{
    __shared__ __align__(16) char lds[64 * 136 * 2];   // 17408 B union:
    short* h1t = (short*)lds;                          //   h1 bf16 [64][136]
    float* h2s = (float*)lds;                          //   h2 f32 [64][65] (aliases after barrier)

    const int t = threadIdx.x;
    const int w = t >> 6, l = t & 63;
    const int q = l >> 4, c = l & 15;
    const int e0 = blockIdx.x * 64;

    // stage h1 = relu(P[src] + D[dst] + b1): 64 rows x 128 cols bf16
#pragma unroll
    for (int j = 0; j < 4; ++j) {
        int idx = t + j * 256;          // 1024 chunks of 8 elems
        int row = idx >> 4, ch = idx & 15;
        int src = csr_src[e0 + row];
        int dst = csr_dst[e0 + row];
        bf16x8 pv = *(const bf16x8*)&PD[(size_t)src * HD + ch * 8];
        bf16x8 dv = *(const bf16x8*)&PD[(size_t)dst * HD + 128 + ch * 8];
        float4 ba = *(const float4*)&b1[ch * 8];
        float4 bb = *(const float4*)&b1[ch * 8 + 4];
        bf16x8 hv;
        hv[0] = (short)fbf(fmaxf(bf2f((unsigned short)pv[0]) + bf2f((unsigned short)dv[0]) + ba.x, 0.f));
        hv[1] = (short)fbf(fmaxf(bf2f((unsigned short)pv[1]) + bf2f((unsigned short)dv[1]) + ba.y, 0.f));
        hv[2] = (short)fbf(fmaxf(bf2f((unsigned short)pv[2]) + bf2f((unsigned short)dv[2]) + ba.z, 0.f));
        hv[3] = (short)fbf(fmaxf(bf2f((unsigned short)pv[3]) + bf2f((unsigned short)dv[3]) + ba.w, 0.f));
        hv[4] = (short)fbf(fmaxf(bf2f((unsigned short)pv[4]) + bf2f((unsigned short)dv[4]) + bb.x, 0.f));
        hv[5] = (short)fbf(fmaxf(bf2f((unsigned short)pv[5]) + bf2f((unsigned short)dv[5]) + bb.y, 0.f));
        hv[6] = (short)fbf(fmaxf(bf2f((unsigned short)pv[6]) + bf2f((unsigned short)dv[6]) + bb.z, 0.f));
        hv[7] = (short)fbf(fmaxf(bf2f((unsigned short)pv[7]) + bf2f((unsigned short)dv[7]) + bb.w, 0.f));
        *(bf16x8*)&h1t[row * 136 + ch * 8] = hv;
    }
    __syncthreads();

    // layer2 MFMA: [64,128] @ [128,64]
    f32x4 acc2[4];
#pragma unroll
    for (int i = 0; i < 4; ++i) acc2[i] = (f32x4){0.f, 0.f, 0.f, 0.f};
#pragma unroll
    for (int kt = 0; kt < 4; ++kt) {
        bf16x8 av = *(const bf16x8*)&h1t[(w * 16 + c) * 136 + kt * 32 + q * 8];
#pragma unroll
        for (int nt = 0; nt < 4; ++nt) {
            bf16x8 bv = *(const bf16x8*)&W2p[(size_t)((kt * 4 + nt) * 64 + l) * 8];
            acc2[nt] = __builtin_amdgcn_mfma_f32_16x16x32_bf16(av, bv, acc2[nt], 0, 0, 0);
        }
    }
    __syncthreads();   // h1 reads done; h2 aliases

#pragma unroll
    for (int nt = 0; nt < 4; ++nt) {
        float bv = b2[nt * 16 + c];
#pragma unroll
        for (int r = 0; r < 4; ++r)
            h2s[(w * 16 + q * 4 + r) * 65 + nt * 16 + c] = fmaxf(acc2[nt][r] + bv, 0.f);
    }
    __syncthreads();

    // layer3: all 256 threads — 4 partials per edge + shfl reduce
    {
        int e = t >> 2, part = t & 3;
        float a = 0.f;
#pragma unroll
        for (int kk = 0; kk < 16; ++kk)
            a += h2s[e * 65 + part * 16 + kk] * W3[part * 16 + kk];
        a += __shfl_xor(a, 1);
        a += __shfl_xor(a, 2);
        if (part == 0)
            rating[csr_eid[e0 + e]] = 4.f / (1.f + __expf(-(a + b3[0]))) + 1.f;
    }
}

extern "C" void kernel_launch(void* const* d_in, const int* in_sizes, int n_in,
                              void* d_out, int out_size, void* d_ws, size_t ws_size,
                              hipStream_t stream) {
    const int*   ei  = (const int*)d_in[0];    // [2, E]
    const float* x   = (const float*)d_in[2];
    const float* mem = (const float*)d_in[3];
    const float* Wq  = (const float*)d_in[4];
    const float* bq  = (const float*)d_in[5];
    const float* Wk  = (const float*)d_in[6];
    const float* bk  = (const float*)d_in[7];
    const float* Wv  = (const float*)d_in[8];
    const float* bv  = (const float*)d_in[9];
    const float* Ws  = (const float*)d_in[10];
    const float* bs  = (const float*)d_in[11];
    const float* W1  = (const float*)d_in[12];
    const float* b1  = (const float*)d_in[13];
    const float* W2  = (const float*)d_in[14];
    const float* b2  = (const float*)d_in[15];
    const float* W3  = (const float*)d_in[16];
    const float* b3  = (const float*)d_in[17];
    float* rating = (float*)d_out;

    // Workspace (~237 MB):
    //   Q  [N,256] bf16 (PD aliases Q after attn_pd)          51.2 MB
    //   KV [N,512] bf16 (lane-interleaved K|V)               102.4 MB
    //   S  [N,256] bf16                                       51.2 MB
    //   H  [N,128] bf16 (x+mem)                               25.6 MB
    //   rp, deg, cursor, csr_*, bsum, packs                   ~6.8 MB
    unsigned short* Q = (unsigned short*)d_ws;
    const size_t NHDe = (size_t)N_NODES * HD;   // 25.6M elements
    unsigned short* KV = Q + NHDe;              // N*512 elements
    unsigned short* S  = KV + 2 * NHDe;
    unsigned short* H  = S + NHDe;              // N*128 elements
    int* rp      = (int*)(H + (size_t)N_NODES * HID);
    int* deg     = rp + N_NODES;
    int* cursor  = deg + N_NODES;
    int* csr_src = cursor + N_NODES;
    int* csr_dst = csr_src + N_EDGES;
    int* csr_eid = csr_dst + N_EDGES;
    int* bsum    = csr_eid + N_EDGES;
    unsigned short* Wp  = (unsigned short*)(bsum + 128);
    unsigned short* Wcp = Wp + 16384 * 8;
    unsigned short* W2p = Wcp + 8192 * 8;
    unsigned short* PD  = Q;   // attn_pd writes PD in place of Q (row-owner-only)

    const int eblk  = (N_EDGES + 255) / 256;
    const int pblk  = (N_NODES * HID / 8 + 255) / 256;   // 6250
    const int gblk  = (N_NODES + 63) / 64;               // 1563

    // CSR build + weight packing (deg and cursor are adjacent -> one memset)
    hipMemsetAsync(deg, 0, sizeof(int) * 2 * N_NODES, stream);
    k_deg<<<eblk, 256, 0, stream>>>(ei, deg);
    k_scan1<<<NB_SCAN, 256, 0, stream>>>(deg, rp, bsum);
    k_scan2<<<1, 256, 0, stream>>>(bsum);
    k_bucket<<<eblk, 256, 0, stream>>>(ei, rp, bsum, cursor, csr_src, csr_dst, csr_eid);
    pack_all<<<100, 256, 0, stream>>>(Wq, Wk, Wv, Ws, W1, W2, Wp, Wcp, W2p);

    // H = bf16(x + mem), one streaming pass
    k_pre<<<pblk, 256, 0, stream>>>(x, mem, H);

    // projections: swapped-operand MFMA, slab-free direct stores
    gemm_qs<<<gblk, 512, 0, stream>>>(H, Wp, bq, bs, Q, S);
    gemm_kv<<<gblk, 512, 0, stream>>>(H, Wp, bk, bv, KV);

    // fused attention + PD GEMM (out-tile stays in LDS; PD overwrites Q)
    attn_pd<<<gblk, 512, 0, stream>>>(rp, bsum, deg, csr_src, Q, KV, S, Wcp, PD);

    // light edge MLP in CSR order
    edge_mlp_pd<<<N_EDGES / 64, 256, 0, stream>>>(
        csr_src, csr_dst, csr_eid, PD, b1, W2p, b2, W3, b3, rating);
}

// Round 8
// 491.442 us; speedup vs baseline: 1.2176x; 1.2176x over previous
//
#include <hip/hip_runtime.h>
#include <math.h>

#define N_NODES 100000
#define N_EDGES 400000
#define HID 128
#define HEADS 4
#define OUT_C 64
#define HD 256   // HEADS*OUT_C
#define SCAN_CHUNK 1024
#define NB_SCAN ((N_NODES + SCAN_CHUNK - 1) / SCAN_CHUNK)   // 98
#define SLAB2 2112   // gemm4 per-wave HALF-slab stride (32*66 ushorts)
#define PSLAB 2576   // attn_pd slab region stride (ushorts; 64*40 + 16 pad)

typedef __attribute__((ext_vector_type(8))) short bf16x8;   // 8 bf16 = 4 VGPRs
typedef __attribute__((ext_vector_type(4))) float f32x4;

// fp32 -> bf16 round-to-nearest-even
__device__ __forceinline__ unsigned short fbf(float f) {
    unsigned u = __float_as_uint(f);
    unsigned r = (u + 0x7fffu + ((u >> 16) & 1u)) >> 16;
    return (unsigned short)r;
}
__device__ __forceinline__ float bf2f(unsigned short u) {
    return __uint_as_float(((unsigned)u) << 16);
}

// async global->LDS, 16B per lane; LDS dest = wave-uniform base + lane*16
__device__ __forceinline__ void gl_lds16(const void* g, void* l) {
    __builtin_amdgcn_global_load_lds(
        (const __attribute__((address_space(1))) unsigned int*)g,
        (__attribute__((address_space(3))) unsigned int*)l,
        16, 0, 0);
}

// ---------- CSR build: degree count ----------
__global__ __launch_bounds__(256) void k_deg(const int* __restrict__ ei,
                                             int* __restrict__ deg) {
    int e = blockIdx.x * 256 + threadIdx.x;
    if (e < N_EDGES) atomicAdd(&deg[ei[N_EDGES + e]], 1);
}

// ---------- scan 1 ----------
__global__ __launch_bounds__(256) void k_scan1(const int* __restrict__ deg,
                                               int* __restrict__ rp,
                                               int* __restrict__ bsum) {
    __shared__ int ts[256];
    int b = blockIdx.x, t = threadIdx.x;
    int base = b * SCAN_CHUNK + t * 4;
    int vv[4];
    int s = 0;
#pragma unroll
    for (int i = 0; i < 4; ++i) {
        int d = (base + i < N_NODES) ? deg[base + i] : 0;
        vv[i] = s;
        s += d;
    }
    ts[t] = s;
    __syncthreads();
    for (int off = 1; off < 256; off <<= 1) {
        int x = (t >= off) ? ts[t - off] : 0;
        __syncthreads();
        ts[t] += x;
        __syncthreads();
    }
    int ex = ts[t] - s;
#pragma unroll
    for (int i = 0; i < 4; ++i)
        if (base + i < N_NODES) rp[base + i] = ex + vv[i];
    if (t == 255) bsum[b] = ts[255];
}

// ---------- scan 2 ----------
__global__ __launch_bounds__(256) void k_scan2(int* __restrict__ bsum) {
    __shared__ int ts[256];
    int t = threadIdx.x;
    int v = (t < NB_SCAN) ? bsum[t] : 0;
    ts[t] = v;
    __syncthreads();
    for (int off = 1; off < 256; off <<= 1) {
        int x = (t >= off) ? ts[t - off] : 0;
        __syncthreads();
        ts[t] += x;
        __syncthreads();
    }
    if (t < NB_SCAN) bsum[t] = ts[t] - v;
}

// ---------- bucket: fill csr_src / csr_dst / csr_eid (rp finalized inline via bsum) ----------
__global__ __launch_bounds__(256) void k_bucket(const int* __restrict__ ei,
                                                const int* __restrict__ rp,
                                                const int* __restrict__ bsum,
                                                int* __restrict__ cursor,
                                                int* __restrict__ csr_src,
                                                int* __restrict__ csr_dst,
                                                int* __restrict__ csr_eid) {
    int e = blockIdx.x * 256 + threadIdx.x;
    if (e >= N_EDGES) return;
    int src = ei[e];
    int d   = ei[N_EDGES + e];
    int idx = atomicAdd(&cursor[d], 1);
    int s   = rp[d] + bsum[d >> 10] + idx;
    csr_src[s] = src;
    csr_dst[s] = d;
    csr_eid[s] = e;
}

// ---------- merged weight packing ----------
__global__ __launch_bounds__(256) void pack_all(
    const float* __restrict__ Wq, const float* __restrict__ Wk,
    const float* __restrict__ Wv, const float* __restrict__ Ws,
    const float* __restrict__ W1, const float* __restrict__ W2,
    unsigned short* __restrict__ Wp, unsigned short* __restrict__ Wcp,
    unsigned short* __restrict__ W2p) {
    int i = blockIdx.x * 256 + threadIdx.x;   // 25600 total
    int lane = i & 63;
    int q = lane >> 4, c = lane & 15;
    if (i < 16384) {
        int nt = (i >> 6) & 15, kt = (i >> 10) & 3, z = i >> 12;
        const float* W = (z == 0) ? Wq : (z == 1) ? Wk : (z == 2) ? Wv : Ws;
#pragma unroll
        for (int j = 0; j < 8; ++j)
            Wp[i * 8 + j] = fbf(W[(kt * 32 + q * 8 + j) * HD + nt * 16 + c]);
    } else if (i < 24576) {
        int ii = i - 16384;
        int nt = (ii >> 6) & 15, kt = ii >> 10;
        int n = nt * 16 + c;
#pragma unroll
        for (int j = 0; j < 8; ++j) {
            int k = kt * 32 + q * 8 + j;
            float v = (n < 128) ? W1[k * 128 + n] : W1[(k + 256) * 128 + (n - 128)];
            Wcp[ii * 8 + j] = fbf(v);
        }
    } else if (i < 25600) {
        int ii = i - 24576;
        int nt = (ii >> 6) & 3, kt = ii >> 8;
#pragma unroll
        for (int j = 0; j < 8; ++j)
            W2p[ii * 8 + j] = fbf(W2[(kt * 32 + q * 8 + j) * 64 + nt * 16 + c]);
    }
}

// ---------- K_pre: H = bf16(x + mem), one streaming pass ----------
__global__ __launch_bounds__(256) void k_pre(const float* __restrict__ x,
                                             const float* __restrict__ mem,
                                             unsigned short* __restrict__ H) {
    int idx = blockIdx.x * 256 + threadIdx.x;      // chunk of 8 elems
    if (idx >= N_NODES * HID / 8) return;          // 1,600,000 chunks
    const float4* x4 = (const float4*)x;
    const float4* m4 = (const float4*)mem;
    float4 a0 = x4[(size_t)idx * 2],     a1 = x4[(size_t)idx * 2 + 1];
    float4 b0 = m4[(size_t)idx * 2],     b1 = m4[(size_t)idx * 2 + 1];
    bf16x8 hv;
    hv[0] = (short)fbf(a0.x + b0.x); hv[1] = (short)fbf(a0.y + b0.y);
    hv[2] = (short)fbf(a0.z + b0.z); hv[3] = (short)fbf(a0.w + b0.w);
    hv[4] = (short)fbf(a1.x + b1.x); hv[5] = (short)fbf(a1.y + b1.y);
    hv[6] = (short)fbf(a1.z + b1.z); hv[7] = (short)fbf(a1.w + b1.w);
    *(bf16x8*)&H[(size_t)idx * 8] = hv;
}

// ---------- gemm4 MFMA pass helper ----------
__device__ __forceinline__ void mfma_pass(f32x4 acc[4][4], const short* As,
        const unsigned short* __restrict__ Wp, int z, int w, int l, int q, int c) {
#pragma unroll
    for (int mt = 0; mt < 4; ++mt)
#pragma unroll
        for (int nt = 0; nt < 4; ++nt) acc[mt][nt] = (f32x4){0.f, 0.f, 0.f, 0.f};
#pragma unroll
    for (int kt = 0; kt < 4; ++kt) {
        bf16x8 af[4];
#pragma unroll
        for (int mt = 0; mt < 4; ++mt) {
            int row  = mt * 16 + c;
            int slot = (kt * 4 + q) ^ (row & 7);
            af[mt] = *(const bf16x8*)&As[row * 128 + slot * 8];
        }
#pragma unroll
        for (int nt = 0; nt < 4; ++nt) {
            bf16x8 bw8 = *(const bf16x8*)&Wp[(size_t)(((z * 4 + kt) * 16 + w * 4 + nt) * 64 + l) * 8];
#pragma unroll
            for (int mt = 0; mt < 4; ++mt)
                acc[mt][nt] = __builtin_amdgcn_mfma_f32_16x16x32_bf16(af[mt], bw8, acc[mt][nt], 0, 0, 0);
        }
    }
}

// store half h (output rows h*32..h*32+32) of acc into the wave's [32][66] slab
__device__ __forceinline__ void slab_half(short* slab, const f32x4 acc[4][4],
        const float bb[4], int h, int q, int c) {
#pragma unroll
    for (int mtl = 0; mtl < 2; ++mtl) {
        int mt = h * 2 + mtl;
#pragma unroll
        for (int nt = 0; nt < 4; ++nt)
#pragma unroll
            for (int r = 0; r < 4; ++r)
                slab[(mtl * 16 + q * 4 + r) * 66 + nt * 16 + c] =
                    (short)fbf(acc[mt][nt][r] + bb[nt]);
    }
}

// ---------- K1: projection GEMM, 2-way y split, HALF-slab (LDS 33.3 KB -> 4 blk/CU) ----------
// y=0: Q pass then S pass (wave-private slab halves, no barriers)
// y=1: K then V; per-half cross-wave capture; merged lane-interleaved KV store
//      (each 16 B of KV written once, full width -> no write amplification)
__global__ __launch_bounds__(256, 4) void gemm4(
    const unsigned short* __restrict__ H,
    const unsigned short* __restrict__ Wp,
    const float* __restrict__ bq, const float* __restrict__ bk,
    const float* __restrict__ bv, const float* __restrict__ bs,
    unsigned short* __restrict__ Q, unsigned short* __restrict__ KV,
    unsigned short* __restrict__ S)
{
    __shared__ __align__(16) short As[64 * 128];      // 16384 B, lives across both passes
    __shared__ __align__(16) short Slab[4 * SLAB2];   // 16896 B (4 x [32][66])

    const int t = threadIdx.x;
    const int w = t >> 6, l = t & 63;
    const int q = l >> 4, c = l & 15;
    const int y  = blockIdx.y;          // 0: Q,S   1: K,V
    const int m0 = blockIdx.x * 64;

    // async stage H tile 64x128 bf16: linear LDS dest, XOR-pre-swizzled global src
#pragma unroll
    for (int i = 0; i < 4; ++i) {
        int rbase = w * 16 + i * 4;
        int r  = rbase + (l >> 4);
        int gr = m0 + r; if (gr >= N_NODES) gr = N_NODES - 1;   // clamp; stores guarded
        int ks = (l & 15) ^ (r & 7);
        gl_lds16(&H[(size_t)gr * HID + ks * 8], &As[rbase * 128]);
    }

    const float* bA = (y == 0) ? bq : bk;
    const float* bB = (y == 0) ? bs : bv;
    const int   zA  = (y == 0) ? 0 : 1;
    const int   zB  = (y == 0) ? 3 : 2;
    float bbA[4], bbB[4];
#pragma unroll
    for (int nt = 0; nt < 4; ++nt) {
        bbA[nt] = bA[w * 64 + nt * 16 + c];
        bbB[nt] = bB[w * 64 + nt * 16 + c];
    }

    __syncthreads();   // As ready

    short* slab = &Slab[w * SLAB2];
    f32x4 acc[4][4];
    ushort4 kreg[16];
    const int koff  = (l & 15) * 4;
    const short* cslab = &Slab[(l >> 4) * SLAB2];   // cross-wave chunk source
    const int hw = w >> 1;          // half containing this wave's 16 output rows
    const int lw = (w & 1) * 16;    // local row base within that half
    const int srow = l >> 3, schk = l & 7;

    // ---- pass A (Q or K) ----
    mfma_pass(acc, As, Wp, zA, w, l, q, c);
    if (y == 0) {
#pragma unroll
        for (int h = 0; h < 2; ++h) {
            slab_half(slab, acc, bbA, h, q, c);     // own-wave region
#pragma unroll
            for (int j = 0; j < 4; ++j) {           // read back own region: no barrier
                int lr = j * 8 + srow;
                int gr = m0 + h * 32 + lr;
                if (gr < N_NODES)
                    *(bf16x8*)&Q[(size_t)gr * HD + w * 64 + schk * 8] =
                        *(const bf16x8*)&slab[lr * 66 + schk * 8];
            }
        }
    } else {
#pragma unroll
        for (int h = 0; h < 2; ++h) {
            slab_half(slab, acc, bbA, h, q, c);
            __syncthreads();                        // K half visible to all waves
            if (hw == h) {
#pragma unroll
                for (int i = 0; i < 16; ++i)        // capture K chunks for rows w*16..+16
                    kreg[i] = *(const ushort4*)&cslab[(lw + i) * 66 + koff];
            }
            __syncthreads();                        // captures done before overwrite
        }
    }

    // ---- pass B (S or V) ----
    mfma_pass(acc, As, Wp, zB, w, l, q, c);
    if (y == 0) {
#pragma unroll
        for (int h = 0; h < 2; ++h) {
            slab_half(slab, acc, bbB, h, q, c);
#pragma unroll
            for (int j = 0; j < 4; ++j) {
                int lr = j * 8 + srow;
                int gr = m0 + h * 32 + lr;
                if (gr < N_NODES)
                    *(bf16x8*)&S[(size_t)gr * HD + w * 64 + schk * 8] =
                        *(const bf16x8*)&slab[lr * 66 + schk * 8];
            }
        }
    } else {
#pragma unroll
        for (int h = 0; h < 2; ++h) {
            slab_half(slab, acc, bbB, h, q, c);
            __syncthreads();                        // V half visible
            if (hw == h) {
#pragma unroll
                for (int i = 0; i < 16; ++i) {
                    int gr = m0 + w * 16 + i;
                    ushort4 vr = *(const ushort4*)&cslab[(lw + i) * 66 + koff];
                    if (gr < N_NODES) {
                        bf16x8 ov;
                        ov[0] = (short)kreg[i].x; ov[1] = (short)kreg[i].y;
                        ov[2] = (short)kreg[i].z; ov[3] = (short)kreg[i].w;
                        ov[4] = (short)vr.x;      ov[5] = (short)vr.y;
                        ov[6] = (short)vr.z;      ov[7] = (short)vr.w;
                        *(bf16x8*)&KV[(size_t)gr * 512 + l * 8] = ov;
                    }
                }
            }
            __syncthreads();                        // before next half overwrites
        }
    }
}

// ---------- K2: fused attention + PD GEMM ----------
// 512 threads = 8 waves; LDS = exactly 32 KB -> 4 blocks/CU (32 waves, 100%).
// Attention writes the out-tile pd-swizzled into As; PD GEMM consumes it; the
// transpose slab runs in TWO rounds (waves 0-3's col-half, then 4-7's) so the
// 20.6 KB slab fully aliases the dead As.
__global__ __launch_bounds__(512, 8) void attn_pd(
    const int* __restrict__ rp, const int* __restrict__ bsum,
    const int* __restrict__ deg, const int* __restrict__ csr_src,
    const unsigned short* __restrict__ Q, const unsigned short* __restrict__ KV,
    const unsigned short* __restrict__ S,
    const unsigned short* __restrict__ Wcp,
    unsigned short* __restrict__ PD)
{
    __shared__ __align__(16) short sh[64 * 256];   // 32768 B: As, slab aliases after GEMM
    short* As = sh;

    const int t = threadIdx.x;
    const int w = t >> 6, l = t & 63;
    const int q = l >> 4, c = l & 15;
    const int m0 = blockIdx.x * 64;

    // node metadata for this wave's 8 nodes, gathered wave-wide once
    int meta = 0;
    {
        int nn = m0 + w * 8 + (l & 7);
        if (nn < N_NODES) {
            if (l < 8)       meta = rp[nn] + bsum[nn >> 10];
            else if (l < 16) meta = deg[nn];
        }
    }

    // ---- attention phase: wave w -> rows w*8 .. w*8+8 ----
    for (int i = 0; i < 8; ++i) {
        int row  = w * 8 + i;
        int node = m0 + row;
        if (node < N_NODES) {
            int start = __shfl(meta, i);
            int cnt   = __shfl(meta, 8 + i);

            float q0, q1, q2, q3;   // pre-scaled by 1/sqrt(64)
            ushort4 su;
            {
                ushort4 u = *(const ushort4*)&Q[(size_t)node * HD + l * 4];
                su = *(const ushort4*)&S[(size_t)node * HD + l * 4];   // hoisted
                q0 = bf2f(u.x) * 0.125f; q1 = bf2f(u.y) * 0.125f;
                q2 = bf2f(u.z) * 0.125f; q3 = bf2f(u.w) * 0.125f;
            }

            float d = 0.f;
            float a0 = 0.f, a1 = 0.f, a2 = 0.f, a3 = 0.f;

            int i2 = 0;
            for (; i2 + 4 <= cnt; i2 += 4) {
                int s0 = csr_src[start + i2];
                int s1 = csr_src[start + i2 + 1];
                int s2 = csr_src[start + i2 + 2];
                int s3 = csr_src[start + i2 + 3];
                bf16x8 k0 = *(const bf16x8*)&KV[(size_t)s0 * 512 + l * 8];
                bf16x8 k1 = *(const bf16x8*)&KV[(size_t)s1 * 512 + l * 8];
                bf16x8 k2 = *(const bf16x8*)&KV[(size_t)s2 * 512 + l * 8];
                bf16x8 k3 = *(const bf16x8*)&KV[(size_t)s3 * 512 + l * 8];
                float sA = q0 * bf2f((unsigned short)k0[0]) + q1 * bf2f((unsigned short)k0[1])
                         + q2 * bf2f((unsigned short)k0[2]) + q3 * bf2f((unsigned short)k0[3]);
                float sB = q0 * bf2f((unsigned short)k1[0]) + q1 * bf2f((unsigned short)k1[1])
                         + q2 * bf2f((unsigned short)k1[2]) + q3 * bf2f((unsigned short)k1[3]);
                float sC = q0 * bf2f((unsigned short)k2[0]) + q1 * bf2f((unsigned short)k2[1])
                         + q2 * bf2f((unsigned short)k2[2]) + q3 * bf2f((unsigned short)k2[3]);
                float sD = q0 * bf2f((unsigned short)k3[0]) + q1 * bf2f((unsigned short)k3[1])
                         + q2 * bf2f((unsigned short)k3[2]) + q3 * bf2f((unsigned short)k3[3]);
                sA += __shfl_xor(sA, 1); sB += __shfl_xor(sB, 1);
                sC += __shfl_xor(sC, 1); sD += __shfl_xor(sD, 1);
                sA += __shfl_xor(sA, 2); sB += __shfl_xor(sB, 2);
                sC += __shfl_xor(sC, 2); sD += __shfl_xor(sD, 2);
                sA += __shfl_xor(sA, 4); sB += __shfl_xor(sB, 4);
                sC += __shfl_xor(sC, 4); sD += __shfl_xor(sD, 4);
                sA += __shfl_xor(sA, 8); sB += __shfl_xor(sB, 8);
                sC += __shfl_xor(sC, 8); sD += __shfl_xor(sD, 8);
                float eA = __expf(sA), eB = __expf(sB), eC = __expf(sC), eD = __expf(sD);
                d += (eA + eB) + (eC + eD);
                a0 += eA * bf2f((unsigned short)k0[4]) + eB * bf2f((unsigned short)k1[4])
                    + eC * bf2f((unsigned short)k2[4]) + eD * bf2f((unsigned short)k3[4]);
                a1 += eA * bf2f((unsigned short)k0[5]) + eB * bf2f((unsigned short)k1[5])
                    + eC * bf2f((unsigned short)k2[5]) + eD * bf2f((unsigned short)k3[5]);
                a2 += eA * bf2f((unsigned short)k0[6]) + eB * bf2f((unsigned short)k1[6])
                    + eC * bf2f((unsigned short)k2[6]) + eD * bf2f((unsigned short)k3[6]);
                a3 += eA * bf2f((unsigned short)k0[7]) + eB * bf2f((unsigned short)k1[7])
                    + eC * bf2f((unsigned short)k2[7]) + eD * bf2f((unsigned short)k3[7]);
            }
            if (i2 + 2 <= cnt) {
                int s0 = csr_src[start + i2];
                int s1 = csr_src[start + i2 + 1];
                bf16x8 k0 = *(const bf16x8*)&KV[(size_t)s0 * 512 + l * 8];
                bf16x8 k1 = *(const bf16x8*)&KV[(size_t)s1 * 512 + l * 8];
                float sA = q0 * bf2f((unsigned short)k0[0]) + q1 * bf2f((unsigned short)k0[1])
                         + q2 * bf2f((unsigned short)k0[2]) + q3 * bf2f((unsigned short)k0[3]);
                float sB = q0 * bf2f((unsigned short)k1[0]) + q1 * bf2f((unsigned short)k1[1])
                         + q2 * bf2f((unsigned short)k1[2]) + q3 * bf2f((unsigned short)k1[3]);
                sA += __shfl_xor(sA, 1); sB += __shfl_xor(sB, 1);
                sA += __shfl_xor(sA, 2); sB += __shfl_xor(sB, 2);
                sA += __shfl_xor(sA, 4); sB += __shfl_xor(sB, 4);
                sA += __shfl_xor(sA, 8); sB += __shfl_xor(sB, 8);
                float eA = __expf(sA), eB = __expf(sB);
                d += eA + eB;
                a0 += eA * bf2f((unsigned short)k0[4]) + eB * bf2f((unsigned short)k1[4]);
                a1 += eA * bf2f((unsigned short)k0[5]) + eB * bf2f((unsigned short)k1[5]);
                a2 += eA * bf2f((unsigned short)k0[6]) + eB * bf2f((unsigned short)k1[6]);
                a3 += eA * bf2f((unsigned short)k0[7]) + eB * bf2f((unsigned short)k1[7]);
                i2 += 2;
            }
            if (i2 < cnt) {
                int s0 = csr_src[start + i2];
                bf16x8 k0 = *(const bf16x8*)&KV[(size_t)s0 * 512 + l * 8];
                float sA = q0 * bf2f((unsigned short)k0[0]) + q1 * bf2f((unsigned short)k0[1])
                         + q2 * bf2f((unsigned short)k0[2]) + q3 * bf2f((unsigned short)k0[3]);
                sA += __shfl_xor(sA, 1);
                sA += __shfl_xor(sA, 2);
                sA += __shfl_xor(sA, 4);
                sA += __shfl_xor(sA, 8);
                float eA = __expf(sA);
                d += eA;
                a0 += eA * bf2f((unsigned short)k0[4]);
                a1 += eA * bf2f((unsigned short)k0[5]);
                a2 += eA * bf2f((unsigned short)k0[6]);
                a3 += eA * bf2f((unsigned short)k0[7]);
            }

            float inv = 1.f / (d + 1e-16f);
            ushort4 ov = make_ushort4(fbf(bf2f(su.x) + a0 * inv),
                                      fbf(bf2f(su.y) + a1 * inv),
                                      fbf(bf2f(su.z) + a2 * inv),
                                      fbf(bf2f(su.w) + a3 * inv));
            // write into PD A-tile, pd-swizzled: logical 16B-chunk lc=l>>1 of row
            // stored at physical chunk lc^(row&7), half (l&1)
            *(ushort4*)&As[row * 256 + (((l >> 1) ^ (row & 7)) << 3) + ((l & 1) << 2)] = ov;
        }
    }
    __syncthreads();   // out-tile complete

    // ---- PD GEMM phase: 8 waves x 2 N-tiles, K=256 ----
    f32x4 acc[4][2];
#pragma unroll
    for (int mt = 0; mt < 4; ++mt)
#pragma unroll
        for (int nt = 0; nt < 2; ++nt) acc[mt][nt] = (f32x4){0.f, 0.f, 0.f, 0.f};

#pragma unroll
    for (int kt = 0; kt < 8; ++kt) {
        bf16x8 af[4];
#pragma unroll
        for (int mt = 0; mt < 4; ++mt) {
            int row  = mt * 16 + c;
            int slot = (kt * 4 + q) ^ (row & 7);
            af[mt] = *(const bf16x8*)&As[row * 256 + slot * 8];
        }
#pragma unroll
        for (int nt = 0; nt < 2; ++nt) {
            int ntg = w * 2 + nt;
            bf16x8 bv8 = *(const bf16x8*)&Wcp[(size_t)((kt * 16 + ntg) * 64 + l) * 8];
#pragma unroll
            for (int mt = 0; mt < 4; ++mt)
                acc[mt][nt] = __builtin_amdgcn_mfma_f32_16x16x32_bf16(af[mt], bv8, acc[mt][nt], 0, 0, 0);
        }
    }
    __syncthreads();   // all As reads done; slab regions alias As

    // ---- two-round transpose epilogue: half h stores cols h*128..h*128+128 ----
#pragma unroll
    for (int h = 0; h < 2; ++h) {
        if ((w >> 2) == h) {
            short* slab = &sh[(w & 3) * PSLAB];   // region holds cols h*128+(w&3)*32 ..+32
#pragma unroll
            for (int nt = 0; nt < 2; ++nt)
#pragma unroll
                for (int mt = 0; mt < 4; ++mt)
#pragma unroll
                    for (int r = 0; r < 4; ++r)
                        slab[(mt * 16 + q * 4 + r) * 40 + nt * 16 + c] =
                            (short)fbf(acc[mt][nt][r]);
        }
        __syncthreads();
        {
            int cl   = l & 15;                       // col-chunk within this half
            int rsub = l >> 4;                       // 0..3
            const short* sb = &sh[(cl >> 2) * PSLAB + (cl & 3) * 8];
#pragma unroll
            for (int i = 0; i < 2; ++i) {
                int row = w * 8 + i * 4 + rsub;
                int gr  = m0 + row;
                if (gr < N_NODES)
                    *(bf16x8*)&PD[(size_t)gr * HD + (h * 16 + cl) * 8] =
                        *(const bf16x8*)&sb[row * 40];
            }
        }
        __syncthreads();   // before next half reuses the same slab regions
    }
}

// ---------- K5: light edge MLP — h1 = relu(P[src]+D[dst]+b1); layer2 MFMA; layer3 ----------
__global__ __launch_bounds__(256) void edge_mlp_pd(
    const int* __restrict__ csr_src, const int* __restrict__ csr_dst,
    const int* __restrict__ csr_eid,
    const unsigned short* __restrict__ PD,
    const float* __restrict__ b1,
    const unsigned short* __restrict__ W2p, const float* __restrict__ b2,
    const float* __restrict__ W3, const float* __restrict__ b3,
    float* __restrict__ rating)
{
    __shared__ __align__(16) char lds[64 * 136 * 2];   // 17408 B union:
    short* h1t = (short*)lds;                          //   h1 bf16 [64][136]
    float* h2s = (float*)lds;                          //   h2 f32 [64][65] (aliases after barrier)

    const int t = threadIdx.x;
    const int w = t >> 6, l = t & 63;
    const int q = l >> 4, c = l & 15;
    const int e0 = blockIdx.x * 64;

    // stage h1 = relu(P[src] + D[dst] + b1): 64 rows x 128 cols bf16
#pragma unroll
    for (int j = 0; j < 4; ++j) {
        int idx = t + j * 256;          // 1024 chunks of 8 elems
        int row = idx >> 4, ch = idx & 15;
        int src = csr_src[e0 + row];
        int dst = csr_dst[e0 + row];
        bf16x8 pv = *(const bf16x8*)&PD[(size_t)src * HD + ch * 8];
        bf16x8 dv = *(const bf16x8*)&PD[(size_t)dst * HD + 128 + ch * 8];
        float4 ba = *(const float4*)&b1[ch * 8];
        float4 bb = *(const float4*)&b1[ch * 8 + 4];
        bf16x8 hv;
        hv[0] = (short)fbf(fmaxf(bf2f((unsigned short)pv[0]) + bf2f((unsigned short)dv[0]) + ba.x, 0.f));
        hv[1] = (short)fbf(fmaxf(bf2f((unsigned short)pv[1]) + bf2f((unsigned short)dv[1]) + ba.y, 0.f));
        hv[2] = (short)fbf(fmaxf(bf2f((unsigned short)pv[2]) + bf2f((unsigned short)dv[2]) + ba.z, 0.f));
        hv[3] = (short)fbf(fmaxf(bf2f((unsigned short)pv[3]) + bf2f((unsigned short)dv[3]) + ba.w, 0.f));
        hv[4] = (short)fbf(fmaxf(bf2f((unsigned short)pv[4]) + bf2f((unsigned short)dv[4]) + bb.x, 0.f));
        hv[5] = (short)fbf(fmaxf(bf2f((unsigned short)pv[5]) + bf2f((unsigned short)dv[5]) + bb.y, 0.f));
        hv[6] = (short)fbf(fmaxf(bf2f((unsigned short)pv[6]) + bf2f((unsigned short)dv[6]) + bb.z, 0.f));
        hv[7] = (short)fbf(fmaxf(bf2f((unsigned short)pv[7]) + bf2f((unsigned short)dv[7]) + bb.w, 0.f));
        *(bf16x8*)&h1t[row * 136 + ch * 8] = hv;
    }
    __syncthreads();

    // layer2 MFMA: [64,128] @ [128,64]
    f32x4 acc2[4];
#pragma unroll
    for (int i = 0; i < 4; ++i) acc2[i] = (f32x4){0.f, 0.f, 0.f, 0.f};
#pragma unroll
    for (int kt = 0; kt < 4; ++kt) {
        bf16x8 av = *(const bf16x8*)&h1t[(w * 16 + c) * 136 + kt * 32 + q * 8];
#pragma unroll
        for (int nt = 0; nt < 4; ++nt) {
            bf16x8 bv = *(const bf16x8*)&W2p[(size_t)((kt * 4 + nt) * 64 + l) * 8];
            acc2[nt] = __builtin_amdgcn_mfma_f32_16x16x32_bf16(av, bv, acc2[nt], 0, 0, 0);
        }
    }
    __syncthreads();   // h1 reads done; h2 aliases

#pragma unroll
    for (int nt = 0; nt < 4; ++nt) {
        float bv = b2[nt * 16 + c];
#pragma unroll
        for (int r = 0; r < 4; ++r)
            h2s[(w * 16 + q * 4 + r) * 65 + nt * 16 + c] = fmaxf(acc2[nt][r] + bv, 0.f);
    }
    __syncthreads();

    // layer3: all 256 threads — 4 partials per edge + shfl reduce
    {
        int e = t >> 2, part = t & 3;
        float a = 0.f;
#pragma unroll
        for (int kk = 0; kk < 16; ++kk)
            a += h2s[e * 65 + part * 16 + kk] * W3[part * 16 + kk];
        a += __shfl_xor(a, 1);
        a += __shfl_xor(a, 2);
        if (part == 0)
            rating[csr_eid[e0 + e]] = 4.f / (1.f + __expf(-(a + b3[0]))) + 1.f;
    }
}

extern "C" void kernel_launch(void* const* d_in, const int* in_sizes, int n_in,
                              void* d_out, int out_size, void* d_ws, size_t ws_size,
                              hipStream_t stream) {
    const int*   ei  = (const int*)d_in[0];    // [2, E]
    const float* x   = (const float*)d_in[2];
    const float* mem = (const float*)d_in[3];
    const float* Wq  = (const float*)d_in[4];
    const float* bq  = (const float*)d_in[5];
    const float* Wk  = (const float*)d_in[6];
    const float* bk  = (const float*)d_in[7];
    const float* Wv  = (const float*)d_in[8];
    const float* bv  = (const float*)d_in[9];
    const float* Ws  = (const float*)d_in[10];
    const float* bs  = (const float*)d_in[11];
    const float* W1  = (const float*)d_in[12];
    const float* b1  = (const float*)d_in[13];
    const float* W2  = (const float*)d_in[14];
    const float* b2  = (const float*)d_in[15];
    const float* W3  = (const float*)d_in[16];
    const float* b3  = (const float*)d_in[17];
    float* rating = (float*)d_out;

    // Workspace (~237 MB):
    //   Q  [N,256] bf16 (PD aliases Q after attn_pd)          51.2 MB
    //   KV [N,512] bf16 (lane-interleaved K|V)               102.4 MB
    //   S  [N,256] bf16                                       51.2 MB
    //   H  [N,128] bf16 (x+mem)                               25.6 MB
    //   rp, deg, cursor, csr_*, bsum, packs                   ~6.8 MB
    unsigned short* Q = (unsigned short*)d_ws;
    const size_t NHDe = (size_t)N_NODES * HD;   // 25.6M elements
    unsigned short* KV = Q + NHDe;              // N*512 elements
    unsigned short* S  = KV + 2 * NHDe;
    unsigned short* H  = S + NHDe;              // N*128 elements
    int* rp      = (int*)(H + (size_t)N_NODES * HID);
    int* deg     = rp + N_NODES;
    int* cursor  = deg + N_NODES;
    int* csr_src = cursor + N_NODES;
    int* csr_dst = csr_src + N_EDGES;
    int* csr_eid = csr_dst + N_EDGES;
    int* bsum    = csr_eid + N_EDGES;
    unsigned short* Wp  = (unsigned short*)(bsum + 128);
    unsigned short* Wcp = Wp + 16384 * 8;
    unsigned short* W2p = Wcp + 8192 * 8;
    unsigned short* PD  = Q;   // attn_pd writes PD in place of Q (row-owner-only)

    const int eblk  = (N_EDGES + 255) / 256;
    const int pblk  = (N_NODES * HID / 8 + 255) / 256;   // 6250
    const int gblk  = (N_NODES + 63) / 64;               // 1563

    // CSR build + weight packing (deg and cursor are adjacent -> one memset)
    hipMemsetAsync(deg, 0, sizeof(int) * 2 * N_NODES, stream);
    k_deg<<<eblk, 256, 0, stream>>>(ei, deg);
    k_scan1<<<NB_SCAN, 256, 0, stream>>>(deg, rp, bsum);
    k_scan2<<<1, 256, 0, stream>>>(bsum);
    k_bucket<<<eblk, 256, 0, stream>>>(ei, rp, bsum, cursor, csr_src, csr_dst, csr_eid);
    pack_all<<<100, 256, 0, stream>>>(Wq, Wk, Wv, Ws, W1, W2, Wp, Wcp, W2p);

    // H = bf16(x + mem), one streaming pass
    k_pre<<<pblk, 256, 0, stream>>>(x, mem, H);

    // projections: y=0 -> Q,S ; y=1 -> K,V (merged interleaved store); half-slab
    gemm4<<<dim3(gblk, 2), dim3(256), 0, stream>>>(
        H, Wp, bq, bk, bv, bs, Q, KV, S);

    // fused attention + PD GEMM (out-tile stays in LDS; PD overwrites Q)
    attn_pd<<<gblk, 512, 0, stream>>>(rp, bsum, deg, csr_src, Q, KV, S, Wcp, PD);

    // light edge MLP in CSR order
    edge_mlp_pd<<<N_EDGES / 64, 256, 0, stream>>>(
        csr_src, csr_dst, csr_eid, PD, b1, W2p, b2, W3, b3, rating);
}

// Round 9
// 419.265 us; speedup vs baseline: 1.4272x; 1.1722x over previous
//
#include <hip/hip_runtime.h>
#include <math.h>

#define N_NODES 100000
#define N_EDGES 400000
#define HID 128
#define HEADS 4
#define OUT_C 64
#define HD 256   // HEADS*OUT_C
#define SCAN_CHUNK 1024
#define NB_SCAN ((N_NODES + SCAN_CHUNK - 1) / SCAN_CHUNK)   // 98
#define SLAB_STRIDE 4356   // gemm4 per-wave slab stride (ushorts; 64*68+4)
#define PSLAB 2560         // attn_pd slab region stride (ushorts; 64*40, no pad -> 40960 B total)

typedef __attribute__((ext_vector_type(8))) short bf16x8;   // 8 bf16 = 4 VGPRs
typedef __attribute__((ext_vector_type(4))) float f32x4;

// fp32 -> bf16 round-to-nearest-even
__device__ __forceinline__ unsigned short fbf(float f) {
    unsigned u = __float_as_uint(f);
    unsigned r = (u + 0x7fffu + ((u >> 16) & 1u)) >> 16;
    return (unsigned short)r;
}
__device__ __forceinline__ float bf2f(unsigned short u) {
    return __uint_as_float(((unsigned)u) << 16);
}

// async global->LDS, 16B per lane; LDS dest = wave-uniform base + lane*16
__device__ __forceinline__ void gl_lds16(const void* g, void* l) {
    __builtin_amdgcn_global_load_lds(
        (const __attribute__((address_space(1))) unsigned int*)g,
        (__attribute__((address_space(3))) unsigned int*)l,
        16, 0, 0);
}

// ---------- CSR build: degree count ----------
__global__ __launch_bounds__(256) void k_deg(const int* __restrict__ ei,
                                             int* __restrict__ deg) {
    int e = blockIdx.x * 256 + threadIdx.x;
    if (e < N_EDGES) atomicAdd(&deg[ei[N_EDGES + e]], 1);
}

// ---------- scan 1 ----------
__global__ __launch_bounds__(256) void k_scan1(const int* __restrict__ deg,
                                               int* __restrict__ rp,
                                               int* __restrict__ bsum) {
    __shared__ int ts[256];
    int b = blockIdx.x, t = threadIdx.x;
    int base = b * SCAN_CHUNK + t * 4;
    int vv[4];
    int s = 0;
#pragma unroll
    for (int i = 0; i < 4; ++i) {
        int d = (base + i < N_NODES) ? deg[base + i] : 0;
        vv[i] = s;
        s += d;
    }
    ts[t] = s;
    __syncthreads();
    for (int off = 1; off < 256; off <<= 1) {
        int x = (t >= off) ? ts[t - off] : 0;
        __syncthreads();
        ts[t] += x;
        __syncthreads();
    }
    int ex = ts[t] - s;
#pragma unroll
    for (int i = 0; i < 4; ++i)
        if (base + i < N_NODES) rp[base + i] = ex + vv[i];
    if (t == 255) bsum[b] = ts[255];
}

// ---------- scan 2 ----------
__global__ __launch_bounds__(256) void k_scan2(int* __restrict__ bsum) {
    __shared__ int ts[256];
    int t = threadIdx.x;
    int v = (t < NB_SCAN) ? bsum[t] : 0;
    ts[t] = v;
    __syncthreads();
    for (int off = 1; off < 256; off <<= 1) {
        int x = (t >= off) ? ts[t - off] : 0;
        __syncthreads();
        ts[t] += x;
        __syncthreads();
    }
    if (t < NB_SCAN) bsum[t] = ts[t] - v;
}

// ---------- bucket: fill csr_src / csr_dst / csr_eid (rp finalized inline via bsum) ----------
__global__ __launch_bounds__(256) void k_bucket(const int* __restrict__ ei,
                                                const int* __restrict__ rp,
                                                const int* __restrict__ bsum,
                                                int* __restrict__ cursor,
                                                int* __restrict__ csr_src,
                                                int* __restrict__ csr_dst,
                                                int* __restrict__ csr_eid) {
    int e = blockIdx.x * 256 + threadIdx.x;
    if (e >= N_EDGES) return;
    int src = ei[e];
    int d   = ei[N_EDGES + e];
    int idx = atomicAdd(&cursor[d], 1);
    int s   = rp[d] + bsum[d >> 10] + idx;
    csr_src[s] = src;
    csr_dst[s] = d;
    csr_eid[s] = e;
}

// ---------- merged weight packing ----------
__global__ __launch_bounds__(256) void pack_all(
    const float* __restrict__ Wq, const float* __restrict__ Wk,
    const float* __restrict__ Wv, const float* __restrict__ Ws,
    const float* __restrict__ W1, const float* __restrict__ W2,
    unsigned short* __restrict__ Wp, unsigned short* __restrict__ Wcp,
    unsigned short* __restrict__ W2p) {
    int i = blockIdx.x * 256 + threadIdx.x;   // 25600 total
    int lane = i & 63;
    int q = lane >> 4, c = lane & 15;
    if (i < 16384) {
        int nt = (i >> 6) & 15, kt = (i >> 10) & 3, z = i >> 12;
        const float* W = (z == 0) ? Wq : (z == 1) ? Wk : (z == 2) ? Wv : Ws;
#pragma unroll
        for (int j = 0; j < 8; ++j)
            Wp[i * 8 + j] = fbf(W[(kt * 32 + q * 8 + j) * HD + nt * 16 + c]);
    } else if (i < 24576) {
        int ii = i - 16384;
        int nt = (ii >> 6) & 15, kt = ii >> 10;
        int n = nt * 16 + c;
#pragma unroll
        for (int j = 0; j < 8; ++j) {
            int k = kt * 32 + q * 8 + j;
            float v = (n < 128) ? W1[k * 128 + n] : W1[(k + 256) * 128 + (n - 128)];
            Wcp[ii * 8 + j] = fbf(v);
        }
    } else if (i < 25600) {
        int ii = i - 24576;
        int nt = (ii >> 6) & 3, kt = ii >> 8;
#pragma unroll
        for (int j = 0; j < 8; ++j)
            W2p[ii * 8 + j] = fbf(W2[(kt * 32 + q * 8 + j) * 64 + nt * 16 + c]);
    }
}

// ---------- K_pre: H = bf16(x + mem), one streaming pass ----------
__global__ __launch_bounds__(256) void k_pre(const float* __restrict__ x,
                                             const float* __restrict__ mem,
                                             unsigned short* __restrict__ H) {
    int idx = blockIdx.x * 256 + threadIdx.x;      // chunk of 8 elems
    if (idx >= N_NODES * HID / 8) return;          // 1,600,000 chunks
    const float4* x4 = (const float4*)x;
    const float4* m4 = (const float4*)mem;
    float4 a0 = x4[(size_t)idx * 2],     a1 = x4[(size_t)idx * 2 + 1];
    float4 b0 = m4[(size_t)idx * 2],     b1 = m4[(size_t)idx * 2 + 1];
    bf16x8 hv;
    hv[0] = (short)fbf(a0.x + b0.x); hv[1] = (short)fbf(a0.y + b0.y);
    hv[2] = (short)fbf(a0.z + b0.z); hv[3] = (short)fbf(a0.w + b0.w);
    hv[4] = (short)fbf(a1.x + b1.x); hv[5] = (short)fbf(a1.y + b1.y);
    hv[6] = (short)fbf(a1.z + b1.z); hv[7] = (short)fbf(a1.w + b1.w);
    *(bf16x8*)&H[(size_t)idx * 8] = hv;
}

// ---------- gemm4 helpers (R5-proven form) ----------
__device__ __forceinline__ void mfma_pass(f32x4 acc[4][4], const short* As,
        const unsigned short* __restrict__ Wp, int z, int w, int l, int q, int c) {
#pragma unroll
    for (int mt = 0; mt < 4; ++mt)
#pragma unroll
        for (int nt = 0; nt < 4; ++nt) acc[mt][nt] = (f32x4){0.f, 0.f, 0.f, 0.f};
#pragma unroll
    for (int kt = 0; kt < 4; ++kt) {
        bf16x8 af[4];
#pragma unroll
        for (int mt = 0; mt < 4; ++mt) {
            int row  = mt * 16 + c;
            int slot = (kt * 4 + q) ^ (row & 7);
            af[mt] = *(const bf16x8*)&As[row * 128 + slot * 8];
        }
#pragma unroll
        for (int nt = 0; nt < 4; ++nt) {
            bf16x8 bw8 = *(const bf16x8*)&Wp[(size_t)(((z * 4 + kt) * 16 + w * 4 + nt) * 64 + l) * 8];
#pragma unroll
            for (int mt = 0; mt < 4; ++mt)
                acc[mt][nt] = __builtin_amdgcn_mfma_f32_16x16x32_bf16(af[mt], bw8, acc[mt][nt], 0, 0, 0);
        }
    }
}

__device__ __forceinline__ void slab_store(short* slab, const f32x4 acc[4][4],
        const float bb[4], int q, int c) {
#pragma unroll
    for (int nt = 0; nt < 4; ++nt)
#pragma unroll
        for (int mt = 0; mt < 4; ++mt)
#pragma unroll
            for (int r = 0; r < 4; ++r)
                slab[(mt * 16 + q * 4 + r) * 68 + nt * 16 + c] =
                    (short)fbf(acc[mt][nt][r] + bb[nt]);
}

__device__ __forceinline__ void store_rows(unsigned short* __restrict__ O,
        const short* slab, int m0, int w, int l) {
    const int srow = l >> 3, schk = l & 7;
#pragma unroll
    for (int j = 0; j < 8; ++j) {
        int row = j * 8 + srow;
        int gr  = m0 + row;
        if (gr < N_NODES)
            *(bf16x8*)&O[(size_t)gr * HD + w * 64 + schk * 8] =
                *(const bf16x8*)&slab[row * 68 + schk * 8];
    }
}

// ---------- K1: projection GEMM, 2-way y split (R5-proven, 77 us) ----------
// y=0: Q pass then S pass (plain [N,256] stores)
// y=1: K then V; merge store -> lane-interleaved KV (each 16 B written once)
__global__ __launch_bounds__(256, 3) void gemm4(
    const unsigned short* __restrict__ H,
    const unsigned short* __restrict__ Wp,
    const float* __restrict__ bq, const float* __restrict__ bk,
    const float* __restrict__ bv, const float* __restrict__ bs,
    unsigned short* __restrict__ Q, unsigned short* __restrict__ KV,
    unsigned short* __restrict__ S)
{
    __shared__ __align__(16) short As[64 * 128];           // 16 KB, lives across both passes
    __shared__ __align__(16) short Slab[4 * SLAB_STRIDE];  // 34848 B

    const int t = threadIdx.x;
    const int w = t >> 6, l = t & 63;
    const int q = l >> 4, c = l & 15;
    const int y  = blockIdx.y;          // 0: Q,S   1: K,V
    const int m0 = blockIdx.x * 64;

    // async stage H tile 64x128 bf16: linear LDS dest, XOR-pre-swizzled global src
#pragma unroll
    for (int i = 0; i < 4; ++i) {
        int rbase = w * 16 + i * 4;
        int r  = rbase + (l >> 4);
        int gr = m0 + r; if (gr >= N_NODES) gr = N_NODES - 1;   // clamp; stores guarded
        int ks = (l & 15) ^ (r & 7);
        gl_lds16(&H[(size_t)gr * HID + ks * 8], &As[rbase * 128]);
    }

    const int   zA  = (y == 0) ? 0 : 1;
    const int   zB  = (y == 0) ? 3 : 2;
    const float* bA = (y == 0) ? bq : bk;
    const float* bB = (y == 0) ? bs : bv;
    float bbA[4], bbB[4];
#pragma unroll
    for (int nt = 0; nt < 4; ++nt) {
        bbA[nt] = bA[w * 64 + nt * 16 + c];
        bbB[nt] = bB[w * 64 + nt * 16 + c];
    }

    __syncthreads();   // As ready

    short* slab = &Slab[w * SLAB_STRIDE];
    f32x4 acc[4][4];
    ushort4 kreg[16];
    const int koff = (l & 15) * 4;
    const short* cslab = &Slab[(l >> 4) * SLAB_STRIDE];   // cross-wave chunk source

    // ---- pass A (Q or K) ----
    mfma_pass(acc, As, Wp, zA, w, l, q, c);
    slab_store(slab, acc, bbA, q, c);
    if (y == 0) {
        store_rows(Q, slab, m0, w, l);        // own-wave slab read: no barrier needed
    } else {
        __syncthreads();                      // K slab visible to all waves
#pragma unroll
        for (int i = 0; i < 16; ++i)          // capture K chunks for rows w*16..+16
            kreg[i] = *(const ushort4*)&cslab[(w * 16 + i) * 68 + koff];
        __syncthreads();                      // all K reads done before V overwrites
    }

    // ---- pass B (S or V) ----
    mfma_pass(acc, As, Wp, zB, w, l, q, c);
    slab_store(slab, acc, bbB, q, c);
    if (y == 0) {
        store_rows(S, slab, m0, w, l);
    } else {
        __syncthreads();                      // V slab visible
#pragma unroll
        for (int i = 0; i < 16; ++i) {
            int gr = m0 + w * 16 + i;
            ushort4 vr = *(const ushort4*)&cslab[(w * 16 + i) * 68 + koff];
            if (gr < N_NODES) {
                bf16x8 ov;
                ov[0] = (short)kreg[i].x; ov[1] = (short)kreg[i].y;
                ov[2] = (short)kreg[i].z; ov[3] = (short)kreg[i].w;
                ov[4] = (short)vr.x;      ov[5] = (short)vr.y;
                ov[6] = (short)vr.z;      ov[7] = (short)vr.w;
                *(bf16x8*)&KV[(size_t)gr * 512 + l * 8] = ov;
            }
        }
    }
}

// ---------- attention micro-helpers ----------
__device__ __forceinline__ float qdot(const bf16x8& k, float q0, float q1, float q2, float q3) {
    return q0 * bf2f((unsigned short)k[0]) + q1 * bf2f((unsigned short)k[1])
         + q2 * bf2f((unsigned short)k[2]) + q3 * bf2f((unsigned short)k[3]);
}
__device__ __forceinline__ void vacc(const bf16x8& k, float e,
        float& a0, float& a1, float& a2, float& a3) {
    a0 += e * bf2f((unsigned short)k[4]); a1 += e * bf2f((unsigned short)k[5]);
    a2 += e * bf2f((unsigned short)k[6]); a3 += e * bf2f((unsigned short)k[7]);
}
__device__ __forceinline__ float wred(float s) {
    s += __shfl_xor(s, 1); s += __shfl_xor(s, 2);
    s += __shfl_xor(s, 4); s += __shfl_xor(s, 8);
    return s;
}
// two edges of one node
__device__ __forceinline__ void attn2(const int* __restrict__ csr, int base,
        const unsigned short* __restrict__ KV, int l,
        float q0, float q1, float q2, float q3,
        float& d, float& a0, float& a1, float& a2, float& a3) {
    int s0 = csr[base], s1 = csr[base + 1];
    bf16x8 k0 = *(const bf16x8*)&KV[(size_t)s0 * 512 + l * 8];
    bf16x8 k1 = *(const bf16x8*)&KV[(size_t)s1 * 512 + l * 8];
    float sA = wred(qdot(k0, q0, q1, q2, q3));
    float sB = wred(qdot(k1, q0, q1, q2, q3));
    float eA = __expf(sA), eB = __expf(sB);
    d += eA + eB;
    vacc(k0, eA, a0, a1, a2, a3);
    vacc(k1, eB, a0, a1, a2, a3);
}
__device__ __forceinline__ void attn1(const int* __restrict__ csr, int base,
        const unsigned short* __restrict__ KV, int l,
        float q0, float q1, float q2, float q3,
        float& d, float& a0, float& a1, float& a2, float& a3) {
    int s0 = csr[base];
    bf16x8 k0 = *(const bf16x8*)&KV[(size_t)s0 * 512 + l * 8];
    float sA = wred(qdot(k0, q0, q1, q2, q3));
    float eA = __expf(sA);
    d += eA;
    vacc(k0, eA, a0, a1, a2, a3);
}

// ---------- K2: fused attention + PD GEMM (paired-node attention) ----------
// 512 threads = 8 waves; LDS = 40960 B (4 blocks/CU feasible); launch_bounds
// kept at (512,6) so VGPR cap stays 85 (R8 lesson: tighter bounds -> spills).
// Wave w computes attention for node pairs (2j,2j+1) with INDEPENDENT online
// sums (4 KV loads in flight from 2 dependency chains), writes the out-tile
// pd-swizzled into As, then the block runs PD = out @ [W1_top|W1_bot].
__global__ __launch_bounds__(512, 6) void attn_pd(
    const int* __restrict__ rp, const int* __restrict__ bsum,
    const int* __restrict__ deg, const int* __restrict__ csr_src,
    const unsigned short* __restrict__ Q, const unsigned short* __restrict__ KV,
    const unsigned short* __restrict__ S,
    const unsigned short* __restrict__ Wcp,
    unsigned short* __restrict__ PD)
{
    __shared__ __align__(16) short sh[8 * PSLAB];   // 40960 B: As (32 KB) + slab alias

    const int t = threadIdx.x;
    const int w = t >> 6, l = t & 63;
    const int q = l >> 4, c = l & 15;
    const int m0 = blockIdx.x * 64;
    short* As = sh;

    // node metadata for this wave's 8 nodes, gathered wave-wide once
    int meta = 0;
    {
        int nn = m0 + w * 8 + (l & 7);
        if (nn < N_NODES) {
            if (l < 8)       meta = rp[nn] + bsum[nn >> 10];
            else if (l < 16) meta = deg[nn];
        }
    }

    // ---- attention phase: 4 node-pairs per wave ----
    for (int j = 0; j < 4; ++j) {
        int rowA = w * 8 + 2 * j, rowB = rowA + 1;
        int nodeA = m0 + rowA, nodeB = m0 + rowB;
        bool vA = nodeA < N_NODES, vB = nodeB < N_NODES;   // wave-uniform
        int startA = __shfl(meta, 2 * j);
        int cntA   = __shfl(meta, 8 + 2 * j);
        int startB = __shfl(meta, 2 * j + 1);
        int cntB   = __shfl(meta, 8 + 2 * j + 1);

        float qA0 = 0.f, qA1 = 0.f, qA2 = 0.f, qA3 = 0.f;
        float qB0 = 0.f, qB1 = 0.f, qB2 = 0.f, qB3 = 0.f;
        ushort4 suA = make_ushort4(0, 0, 0, 0), suB = make_ushort4(0, 0, 0, 0);
        if (vA) {
            ushort4 u = *(const ushort4*)&Q[(size_t)nodeA * HD + l * 4];
            suA = *(const ushort4*)&S[(size_t)nodeA * HD + l * 4];
            qA0 = bf2f(u.x) * 0.125f; qA1 = bf2f(u.y) * 0.125f;
            qA2 = bf2f(u.z) * 0.125f; qA3 = bf2f(u.w) * 0.125f;
        }
        if (vB) {
            ushort4 u = *(const ushort4*)&Q[(size_t)nodeB * HD + l * 4];
            suB = *(const ushort4*)&S[(size_t)nodeB * HD + l * 4];
            qB0 = bf2f(u.x) * 0.125f; qB1 = bf2f(u.y) * 0.125f;
            qB2 = bf2f(u.z) * 0.125f; qB3 = bf2f(u.w) * 0.125f;
        }

        float dA = 0.f, aA0 = 0.f, aA1 = 0.f, aA2 = 0.f, aA3 = 0.f;
        float dB = 0.f, aB0 = 0.f, aB1 = 0.f, aB2 = 0.f, aB3 = 0.f;
        int iA = 0, iB = 0;

        // paired main loop: 2 edges of A + 2 edges of B, independent chains
        while (iA + 2 <= cntA && iB + 2 <= cntB) {
            int s0 = csr_src[startA + iA], s1 = csr_src[startA + iA + 1];
            int s2 = csr_src[startB + iB], s3 = csr_src[startB + iB + 1];
            bf16x8 k0 = *(const bf16x8*)&KV[(size_t)s0 * 512 + l * 8];
            bf16x8 k1 = *(const bf16x8*)&KV[(size_t)s1 * 512 + l * 8];
            bf16x8 k2 = *(const bf16x8*)&KV[(size_t)s2 * 512 + l * 8];
            bf16x8 k3 = *(const bf16x8*)&KV[(size_t)s3 * 512 + l * 8];
            float sA = qdot(k0, qA0, qA1, qA2, qA3);
            float sB = qdot(k1, qA0, qA1, qA2, qA3);
            float sC = qdot(k2, qB0, qB1, qB2, qB3);
            float sD = qdot(k3, qB0, qB1, qB2, qB3);
            sA += __shfl_xor(sA, 1); sB += __shfl_xor(sB, 1);
            sC += __shfl_xor(sC, 1); sD += __shfl_xor(sD, 1);
            sA += __shfl_xor(sA, 2); sB += __shfl_xor(sB, 2);
            sC += __shfl_xor(sC, 2); sD += __shfl_xor(sD, 2);
            sA += __shfl_xor(sA, 4); sB += __shfl_xor(sB, 4);
            sC += __shfl_xor(sC, 4); sD += __shfl_xor(sD, 4);
            sA += __shfl_xor(sA, 8); sB += __shfl_xor(sB, 8);
            sC += __shfl_xor(sC, 8); sD += __shfl_xor(sD, 8);
            float eA = __expf(sA), eB = __expf(sB), eC = __expf(sC), eD = __expf(sD);
            dA += eA + eB;
            dB += eC + eD;
            vacc(k0, eA, aA0, aA1, aA2, aA3);
            vacc(k1, eB, aA0, aA1, aA2, aA3);
            vacc(k2, eC, aB0, aB1, aB2, aB3);
            vacc(k3, eD, aB0, aB1, aB2, aB3);
            iA += 2; iB += 2;
        }
        // drain A
        for (; iA + 2 <= cntA; iA += 2)
            attn2(csr_src, startA + iA, KV, l, qA0, qA1, qA2, qA3, dA, aA0, aA1, aA2, aA3);
        if (iA < cntA)
            attn1(csr_src, startA + iA, KV, l, qA0, qA1, qA2, qA3, dA, aA0, aA1, aA2, aA3);
        // drain B
        for (; iB + 2 <= cntB; iB += 2)
            attn2(csr_src, startB + iB, KV, l, qB0, qB1, qB2, qB3, dB, aB0, aB1, aB2, aB3);
        if (iB < cntB)
            attn1(csr_src, startB + iB, KV, l, qB0, qB1, qB2, qB3, dB, aB0, aB1, aB2, aB3);

        // finalize + write into PD A-tile, pd-swizzled:
        // logical 16B-chunk lc=l>>1 of row stored at chunk lc^(row&7), half (l&1)
        if (vA) {
            float inv = 1.f / (dA + 1e-16f);
            ushort4 ov = make_ushort4(fbf(bf2f(suA.x) + aA0 * inv),
                                      fbf(bf2f(suA.y) + aA1 * inv),
                                      fbf(bf2f(suA.z) + aA2 * inv),
                                      fbf(bf2f(suA.w) + aA3 * inv));
            *(ushort4*)&As[rowA * 256 + (((l >> 1) ^ (rowA & 7)) << 3) + ((l & 1) << 2)] = ov;
        }
        if (vB) {
            float inv = 1.f / (dB + 1e-16f);
            ushort4 ov = make_ushort4(fbf(bf2f(suB.x) + aB0 * inv),
                                      fbf(bf2f(suB.y) + aB1 * inv),
                                      fbf(bf2f(suB.z) + aB2 * inv),
                                      fbf(bf2f(suB.w) + aB3 * inv));
            *(ushort4*)&As[rowB * 256 + (((l >> 1) ^ (rowB & 7)) << 3) + ((l & 1) << 2)] = ov;
        }
    }
    __syncthreads();   // out-tile complete

    // ---- PD GEMM phase: 8 waves x 2 N-tiles, K=256 ----
    f32x4 acc[4][2];
#pragma unroll
    for (int mt = 0; mt < 4; ++mt)
#pragma unroll
        for (int nt = 0; nt < 2; ++nt) acc[mt][nt] = (f32x4){0.f, 0.f, 0.f, 0.f};

#pragma unroll
    for (int kt = 0; kt < 8; ++kt) {
        bf16x8 af[4];
#pragma unroll
        for (int mt = 0; mt < 4; ++mt) {
            int row  = mt * 16 + c;
            int slot = (kt * 4 + q) ^ (row & 7);
            af[mt] = *(const bf16x8*)&As[row * 256 + slot * 8];
        }
#pragma unroll
        for (int nt = 0; nt < 2; ++nt) {
            int ntg = w * 2 + nt;
            bf16x8 bv8 = *(const bf16x8*)&Wcp[(size_t)((kt * 16 + ntg) * 64 + l) * 8];
#pragma unroll
            for (int mt = 0; mt < 4; ++mt)
                acc[mt][nt] = __builtin_amdgcn_mfma_f32_16x16x32_bf16(af[mt], bv8, acc[mt][nt], 0, 0, 0);
        }
    }
    __syncthreads();   // all As reads done; slab regions alias As

    short* slab = &sh[w * PSLAB];   // [64][40], cols w*32..w*32+32
#pragma unroll
    for (int nt = 0; nt < 2; ++nt)
#pragma unroll
        for (int mt = 0; mt < 4; ++mt)
#pragma unroll
            for (int r = 0; r < 4; ++r)
                slab[(mt * 16 + q * 4 + r) * 40 + nt * 16 + c] =
                    (short)fbf(acc[mt][nt][r]);
    __syncthreads();   // slabs visible cross-wave

    // store: wave w stores rows w*8..w*8+8; lane l -> col-chunk cc=l&31 (8 cols)
    const int cc = l & 31;
    const short* sb = &sh[(cc >> 2) * PSLAB + (cc & 3) * 8];
#pragma unroll
    for (int i = 0; i < 4; ++i) {
        int row = w * 8 + i * 2 + (l >> 5);
        int gr  = m0 + row;
        if (gr < N_NODES)
            *(bf16x8*)&PD[(size_t)gr * HD + cc * 8] = *(const bf16x8*)&sb[row * 40];
    }
}

// ---------- K5: light edge MLP — h1 = relu(P[src]+D[dst]+b1); layer2 MFMA; layer3 ----------
__global__ __launch_bounds__(256) void edge_mlp_pd(
    const int* __restrict__ csr_src, const int* __restrict__ csr_dst,
    const int* __restrict__ csr_eid,
    const unsigned short* __restrict__ PD,
    const float* __restrict__ b1,
    const unsigned short* __restrict__ W2p, const float* __restrict__ b2,
    const float* __restrict__ W3, const float* __restrict__ b3,
    float* __restrict__ rating)
{
    __shared__ __align__(16) char lds[64 * 136 * 2];   // 17408 B union:
    short* h1t = (short*)lds;                          //   h1 bf16 [64][136]
    float* h2s = (float*)lds;                          //   h2 f32 [64][65] (aliases after barrier)

    const int t = threadIdx.x;
    const int w = t >> 6, l = t & 63;
    const int q = l >> 4, c = l & 15;
    const int e0 = blockIdx.x * 64;

    // stage h1 = relu(P[src] + D[dst] + b1): 64 rows x 128 cols bf16
#pragma unroll
    for (int j = 0; j < 4; ++j) {
        int idx = t + j * 256;          // 1024 chunks of 8 elems
        int row = idx >> 4, ch = idx & 15;
        int src = csr_src[e0 + row];
        int dst = csr_dst[e0 + row];
        bf16x8 pv = *(const bf16x8*)&PD[(size_t)src * HD + ch * 8];
        bf16x8 dv = *(const bf16x8*)&PD[(size_t)dst * HD + 128 + ch * 8];
        float4 ba = *(const float4*)&b1[ch * 8];
        float4 bb = *(const float4*)&b1[ch * 8 + 4];
        bf16x8 hv;
        hv[0] = (short)fbf(fmaxf(bf2f((unsigned short)pv[0]) + bf2f((unsigned short)dv[0]) + ba.x, 0.f));
        hv[1] = (short)fbf(fmaxf(bf2f((unsigned short)pv[1]) + bf2f((unsigned short)dv[1]) + ba.y, 0.f));
        hv[2] = (short)fbf(fmaxf(bf2f((unsigned short)pv[2]) + bf2f((unsigned short)dv[2]) + ba.z, 0.f));
        hv[3] = (short)fbf(fmaxf(bf2f((unsigned short)pv[3]) + bf2f((unsigned short)dv[3]) + ba.w, 0.f));
        hv[4] = (short)fbf(fmaxf(bf2f((unsigned short)pv[4]) + bf2f((unsigned short)dv[4]) + bb.x, 0.f));
        hv[5] = (short)fbf(fmaxf(bf2f((unsigned short)pv[5]) + bf2f((unsigned short)dv[5]) + bb.y, 0.f));
        hv[6] = (short)fbf(fmaxf(bf2f((unsigned short)pv[6]) + bf2f((unsigned short)dv[6]) + bb.z, 0.f));
        hv[7] = (short)fbf(fmaxf(bf2f((unsigned short)pv[7]) + bf2f((unsigned short)dv[7]) + bb.w, 0.f));
        *(bf16x8*)&h1t[row * 136 + ch * 8] = hv;
    }
    __syncthreads();

    // layer2 MFMA: [64,128] @ [128,64]
    f32x4 acc2[4];
#pragma unroll
    for (int i = 0; i < 4; ++i) acc2[i] = (f32x4){0.f, 0.f, 0.f, 0.f};
#pragma unroll
    for (int kt = 0; kt < 4; ++kt) {
        bf16x8 av = *(const bf16x8*)&h1t[(w * 16 + c) * 136 + kt * 32 + q * 8];
#pragma unroll
        for (int nt = 0; nt < 4; ++nt) {
            bf16x8 bv = *(const bf16x8*)&W2p[(size_t)((kt * 4 + nt) * 64 + l) * 8];
            acc2[nt] = __builtin_amdgcn_mfma_f32_16x16x32_bf16(av, bv, acc2[nt], 0, 0, 0);
        }
    }
    __syncthreads();   // h1 reads done; h2 aliases

#pragma unroll
    for (int nt = 0; nt < 4; ++nt) {
        float bv = b2[nt * 16 + c];
#pragma unroll
        for (int r = 0; r < 4; ++r)
            h2s[(w * 16 + q * 4 + r) * 65 + nt * 16 + c] = fmaxf(acc2[nt][r] + bv, 0.f);
    }
    __syncthreads();

    // layer3: all 256 threads — 4 partials per edge + shfl reduce
    {
        int e = t >> 2, part = t & 3;
        float a = 0.f;
#pragma unroll
        for (int kk = 0; kk < 16; ++kk)
            a += h2s[e * 65 + part * 16 + kk] * W3[part * 16 + kk];
        a += __shfl_xor(a, 1);
        a += __shfl_xor(a, 2);
        if (part == 0)
            rating[csr_eid[e0 + e]] = 4.f / (1.f + __expf(-(a + b3[0]))) + 1.f;
    }
}

extern "C" void kernel_launch(void* const* d_in, const int* in_sizes, int n_in,
                              void* d_out, int out_size, void* d_ws, size_t ws_size,
                              hipStream_t stream) {
    const int*   ei  = (const int*)d_in[0];    // [2, E]
    const float* x   = (const float*)d_in[2];
    const float* mem = (const float*)d_in[3];
    const float* Wq  = (const float*)d_in[4];
    const float* bq  = (const float*)d_in[5];
    const float* Wk  = (const float*)d_in[6];
    const float* bk  = (const float*)d_in[7];
    const float* Wv  = (const float*)d_in[8];
    const float* bv  = (const float*)d_in[9];
    const float* Ws  = (const float*)d_in[10];
    const float* bs  = (const float*)d_in[11];
    const float* W1  = (const float*)d_in[12];
    const float* b1  = (const float*)d_in[13];
    const float* W2  = (const float*)d_in[14];
    const float* b2  = (const float*)d_in[15];
    const float* W3  = (const float*)d_in[16];
    const float* b3  = (const float*)d_in[17];
    float* rating = (float*)d_out;

    // Workspace (~237 MB):
    //   Q  [N,256] bf16 (PD aliases Q after attn_pd)          51.2 MB
    //   KV [N,512] bf16 (lane-interleaved K|V)               102.4 MB
    //   S  [N,256] bf16                                       51.2 MB
    //   H  [N,128] bf16 (x+mem)                               25.6 MB
    //   rp, deg, cursor, csr_*, bsum, packs                   ~6.8 MB
    unsigned short* Q = (unsigned short*)d_ws;
    const size_t NHDe = (size_t)N_NODES * HD;   // 25.6M elements
    unsigned short* KV = Q + NHDe;              // N*512 elements
    unsigned short* S  = KV + 2 * NHDe;
    unsigned short* H  = S + NHDe;              // N*128 elements
    int* rp      = (int*)(H + (size_t)N_NODES * HID);
    int* deg     = rp + N_NODES;
    int* cursor  = deg + N_NODES;
    int* csr_src = cursor + N_NODES;
    int* csr_dst = csr_src + N_EDGES;
    int* csr_eid = csr_dst + N_EDGES;
    int* bsum    = csr_eid + N_EDGES;
    unsigned short* Wp  = (unsigned short*)(bsum + 128);
    unsigned short* Wcp = Wp + 16384 * 8;
    unsigned short* W2p = Wcp + 8192 * 8;
    unsigned short* PD  = Q;   // attn_pd writes PD in place of Q (row-owner-only)

    const int eblk  = (N_EDGES + 255) / 256;
    const int pblk  = (N_NODES * HID / 8 + 255) / 256;   // 6250
    const int gblk  = (N_NODES + 63) / 64;               // 1563

    // CSR build + weight packing (deg and cursor are adjacent -> one memset)
    hipMemsetAsync(deg, 0, sizeof(int) * 2 * N_NODES, stream);
    k_deg<<<eblk, 256, 0, stream>>>(ei, deg);
    k_scan1<<<NB_SCAN, 256, 0, stream>>>(deg, rp, bsum);
    k_scan2<<<1, 256, 0, stream>>>(bsum);
    k_bucket<<<eblk, 256, 0, stream>>>(ei, rp, bsum, cursor, csr_src, csr_dst, csr_eid);
    pack_all<<<100, 256, 0, stream>>>(Wq, Wk, Wv, Ws, W1, W2, Wp, Wcp, W2p);

    // H = bf16(x + mem), one streaming pass
    k_pre<<<pblk, 256, 0, stream>>>(x, mem, H);

    // projections: y=0 -> Q,S ; y=1 -> K,V (merged interleaved store)
    gemm4<<<dim3(gblk, 2), dim3(256), 0, stream>>>(
        H, Wp, bq, bk, bv, bs, Q, KV, S);

    // fused attention + PD GEMM (paired-node attention; PD overwrites Q)
    attn_pd<<<gblk, 512, 0, stream>>>(rp, bsum, deg, csr_src, Q, KV, S, Wcp, PD);

    // light edge MLP in CSR order
    edge_mlp_pd<<<N_EDGES / 64, 256, 0, stream>>>(
        csr_src, csr_dst, csr_eid, PD, b1, W2p, b2, W3, b3, rating);
}

// Round 10
// 418.442 us; speedup vs baseline: 1.4300x; 1.0020x over previous
//
#include <hip/hip_runtime.h>
#include <math.h>

#define N_NODES 100000
#define N_EDGES 400000
#define HID 128
#define HEADS 4
#define OUT_C 64
#define HD 256   // HEADS*OUT_C
#define SCAN_CHUNK 1024
#define NB_SCAN ((N_NODES + SCAN_CHUNK - 1) / SCAN_CHUNK)   // 98
#define SLAB_STRIDE 4356   // gemm4 per-wave slab stride (ushorts; 64*68+4)
#define PSLAB 2560         // attn_pd slab region stride (ushorts; 64*40 -> 40960 B total)

typedef __attribute__((ext_vector_type(8))) short bf16x8;   // 8 bf16 = 4 VGPRs
typedef __attribute__((ext_vector_type(4))) float f32x4;

// fp32 -> bf16 round-to-nearest-even
__device__ __forceinline__ unsigned short fbf(float f) {
    unsigned u = __float_as_uint(f);
    unsigned r = (u + 0x7fffu + ((u >> 16) & 1u)) >> 16;
    return (unsigned short)r;
}
__device__ __forceinline__ float bf2f(unsigned short u) {
    return __uint_as_float(((unsigned)u) << 16);
}

// async global->LDS, 16B per lane; LDS dest = wave-uniform base + lane*16
__device__ __forceinline__ void gl_lds16(const void* g, void* l) {
    __builtin_amdgcn_global_load_lds(
        (const __attribute__((address_space(1))) unsigned int*)g,
        (__attribute__((address_space(3))) unsigned int*)l,
        16, 0, 0);
}

// ---------- CSR build: degree count ----------
__global__ __launch_bounds__(256) void k_deg(const int* __restrict__ ei,
                                             int* __restrict__ deg) {
    int e = blockIdx.x * 256 + threadIdx.x;
    if (e < N_EDGES) atomicAdd(&deg[ei[N_EDGES + e]], 1);
}

// ---------- scan 1 ----------
__global__ __launch_bounds__(256) void k_scan1(const int* __restrict__ deg,
                                               int* __restrict__ rp,
                                               int* __restrict__ bsum) {
    __shared__ int ts[256];
    int b = blockIdx.x, t = threadIdx.x;
    int base = b * SCAN_CHUNK + t * 4;
    int vv[4];
    int s = 0;
#pragma unroll
    for (int i = 0; i < 4; ++i) {
        int d = (base + i < N_NODES) ? deg[base + i] : 0;
        vv[i] = s;
        s += d;
    }
    ts[t] = s;
    __syncthreads();
    for (int off = 1; off < 256; off <<= 1) {
        int x = (t >= off) ? ts[t - off] : 0;
        __syncthreads();
        ts[t] += x;
        __syncthreads();
    }
    int ex = ts[t] - s;
#pragma unroll
    for (int i = 0; i < 4; ++i)
        if (base + i < N_NODES) rp[base + i] = ex + vv[i];
    if (t == 255) bsum[b] = ts[255];
}

// ---------- scan 2 ----------
__global__ __launch_bounds__(256) void k_scan2(int* __restrict__ bsum) {
    __shared__ int ts[256];
    int t = threadIdx.x;
    int v = (t < NB_SCAN) ? bsum[t] : 0;
    ts[t] = v;
    __syncthreads();
    for (int off = 1; off < 256; off <<= 1) {
        int x = (t >= off) ? ts[t - off] : 0;
        __syncthreads();
        ts[t] += x;
        __syncthreads();
    }
    if (t < NB_SCAN) bsum[t] = ts[t] - v;
}

// ---------- bucket: fill csr_src / csr_dst / csr_eid (rp finalized inline via bsum) ----------
__global__ __launch_bounds__(256) void k_bucket(const int* __restrict__ ei,
                                                const int* __restrict__ rp,
                                                const int* __restrict__ bsum,
                                                int* __restrict__ cursor,
                                                int* __restrict__ csr_src,
                                                int* __restrict__ csr_dst,
                                                int* __restrict__ csr_eid) {
    int e = blockIdx.x * 256 + threadIdx.x;
    if (e >= N_EDGES) return;
    int src = ei[e];
    int d   = ei[N_EDGES + e];
    int idx = atomicAdd(&cursor[d], 1);
    int s   = rp[d] + bsum[d >> 10] + idx;
    csr_src[s] = src;
    csr_dst[s] = d;
    csr_eid[s] = e;
}

// ---------- merged weight packing ----------
__global__ __launch_bounds__(256) void pack_all(
    const float* __restrict__ Wq, const float* __restrict__ Wk,
    const float* __restrict__ Wv, const float* __restrict__ Ws,
    const float* __restrict__ W1, const float* __restrict__ W2,
    unsigned short* __restrict__ Wp, unsigned short* __restrict__ Wcp,
    unsigned short* __restrict__ W2p) {
    int i = blockIdx.x * 256 + threadIdx.x;   // 25600 total
    int lane = i & 63;
    int q = lane >> 4, c = lane & 15;
    if (i < 16384) {
        int nt = (i >> 6) & 15, kt = (i >> 10) & 3, z = i >> 12;
        const float* W = (z == 0) ? Wq : (z == 1) ? Wk : (z == 2) ? Wv : Ws;
#pragma unroll
        for (int j = 0; j < 8; ++j)
            Wp[i * 8 + j] = fbf(W[(kt * 32 + q * 8 + j) * HD + nt * 16 + c]);
    } else if (i < 24576) {
        int ii = i - 16384;
        int nt = (ii >> 6) & 15, kt = ii >> 10;
        int n = nt * 16 + c;
#pragma unroll
        for (int j = 0; j < 8; ++j) {
            int k = kt * 32 + q * 8 + j;
            float v = (n < 128) ? W1[k * 128 + n] : W1[(k + 256) * 128 + (n - 128)];
            Wcp[ii * 8 + j] = fbf(v);
        }
    } else if (i < 25600) {
        int ii = i - 24576;
        int nt = (ii >> 6) & 3, kt = ii >> 8;
#pragma unroll
        for (int j = 0; j < 8; ++j)
            W2p[ii * 8 + j] = fbf(W2[(kt * 32 + q * 8 + j) * 64 + nt * 16 + c]);
    }
}

// ---------- K_pre: H = bf16(x + mem), one streaming pass ----------
__global__ __launch_bounds__(256) void k_pre(const float* __restrict__ x,
                                             const float* __restrict__ mem,
                                             unsigned short* __restrict__ H) {
    int idx = blockIdx.x * 256 + threadIdx.x;      // chunk of 8 elems
    if (idx >= N_NODES * HID / 8) return;          // 1,600,000 chunks
    const float4* x4 = (const float4*)x;
    const float4* m4 = (const float4*)mem;
    float4 a0 = x4[(size_t)idx * 2],     a1 = x4[(size_t)idx * 2 + 1];
    float4 b0 = m4[(size_t)idx * 2],     b1 = m4[(size_t)idx * 2 + 1];
    bf16x8 hv;
    hv[0] = (short)fbf(a0.x + b0.x); hv[1] = (short)fbf(a0.y + b0.y);
    hv[2] = (short)fbf(a0.z + b0.z); hv[3] = (short)fbf(a0.w + b0.w);
    hv[4] = (short)fbf(a1.x + b1.x); hv[5] = (short)fbf(a1.y + b1.y);
    hv[6] = (short)fbf(a1.z + b1.z); hv[7] = (short)fbf(a1.w + b1.w);
    *(bf16x8*)&H[(size_t)idx * 8] = hv;
}

// ---------- gemm4 helpers (R5-proven form) ----------
__device__ __forceinline__ void mfma_pass(f32x4 acc[4][4], const short* As,
        const unsigned short* __restrict__ Wp, int z, int w, int l, int q, int c) {
#pragma unroll
    for (int mt = 0; mt < 4; ++mt)
#pragma unroll
        for (int nt = 0; nt < 4; ++nt) acc[mt][nt] = (f32x4){0.f, 0.f, 0.f, 0.f};
#pragma unroll
    for (int kt = 0; kt < 4; ++kt) {
        bf16x8 af[4];
#pragma unroll
        for (int mt = 0; mt < 4; ++mt) {
            int row  = mt * 16 + c;
            int slot = (kt * 4 + q) ^ (row & 7);
            af[mt] = *(const bf16x8*)&As[row * 128 + slot * 8];
        }
#pragma unroll
        for (int nt = 0; nt < 4; ++nt) {
            bf16x8 bw8 = *(const bf16x8*)&Wp[(size_t)(((z * 4 + kt) * 16 + w * 4 + nt) * 64 + l) * 8];
#pragma unroll
            for (int mt = 0; mt < 4; ++mt)
                acc[mt][nt] = __builtin_amdgcn_mfma_f32_16x16x32_bf16(af[mt], bw8, acc[mt][nt], 0, 0, 0);
        }
    }
}

__device__ __forceinline__ void slab_store(short* slab, const f32x4 acc[4][4],
        const float bb[4], int q, int c) {
#pragma unroll
    for (int nt = 0; nt < 4; ++nt)
#pragma unroll
        for (int mt = 0; mt < 4; ++mt)
#pragma unroll
            for (int r = 0; r < 4; ++r)
                slab[(mt * 16 + q * 4 + r) * 68 + nt * 16 + c] =
                    (short)fbf(acc[mt][nt][r] + bb[nt]);
}

__device__ __forceinline__ void store_rows(unsigned short* __restrict__ O,
        const short* slab, int m0, int w, int l) {
    const int srow = l >> 3, schk = l & 7;
#pragma unroll
    for (int j = 0; j < 8; ++j) {
        int row = j * 8 + srow;
        int gr  = m0 + row;
        if (gr < N_NODES)
            *(bf16x8*)&O[(size_t)gr * HD + w * 64 + schk * 8] =
                *(const bf16x8*)&slab[row * 68 + schk * 8];
    }
}

// ---------- K1: projection GEMM, 2-way y split (R5-proven, 77 us) ----------
// y=0: Q pass then S pass (plain [N,256] stores)
// y=1: K then V; merge store -> lane-interleaved KV (each 16 B written once)
__global__ __launch_bounds__(256, 3) void gemm4(
    const unsigned short* __restrict__ H,
    const unsigned short* __restrict__ Wp,
    const float* __restrict__ bq, const float* __restrict__ bk,
    const float* __restrict__ bv, const float* __restrict__ bs,
    unsigned short* __restrict__ Q, unsigned short* __restrict__ KV,
    unsigned short* __restrict__ S)
{
    __shared__ __align__(16) short As[64 * 128];           // 16 KB, lives across both passes
    __shared__ __align__(16) short Slab[4 * SLAB_STRIDE];  // 34848 B

    const int t = threadIdx.x;
    const int w = t >> 6, l = t & 63;
    const int q = l >> 4, c = l & 15;
    const int y  = blockIdx.y;          // 0: Q,S   1: K,V
    const int m0 = blockIdx.x * 64;

    // async stage H tile 64x128 bf16: linear LDS dest, XOR-pre-swizzled global src
#pragma unroll
    for (int i = 0; i < 4; ++i) {
        int rbase = w * 16 + i * 4;
        int r  = rbase + (l >> 4);
        int gr = m0 + r; if (gr >= N_NODES) gr = N_NODES - 1;   // clamp; stores guarded
        int ks = (l & 15) ^ (r & 7);
        gl_lds16(&H[(size_t)gr * HID + ks * 8], &As[rbase * 128]);
    }

    const int   zA  = (y == 0) ? 0 : 1;
    const int   zB  = (y == 0) ? 3 : 2;
    const float* bA = (y == 0) ? bq : bk;
    const float* bB = (y == 0) ? bs : bv;
    float bbA[4], bbB[4];
#pragma unroll
    for (int nt = 0; nt < 4; ++nt) {
        bbA[nt] = bA[w * 64 + nt * 16 + c];
        bbB[nt] = bB[w * 64 + nt * 16 + c];
    }

    __syncthreads();   // As ready

    short* slab = &Slab[w * SLAB_STRIDE];
    f32x4 acc[4][4];
    ushort4 kreg[16];
    const int koff = (l & 15) * 4;
    const short* cslab = &Slab[(l >> 4) * SLAB_STRIDE];   // cross-wave chunk source

    // ---- pass A (Q or K) ----
    mfma_pass(acc, As, Wp, zA, w, l, q, c);
    slab_store(slab, acc, bbA, q, c);
    if (y == 0) {
        store_rows(Q, slab, m0, w, l);        // own-wave slab read: no barrier needed
    } else {
        __syncthreads();                      // K slab visible to all waves
#pragma unroll
        for (int i = 0; i < 16; ++i)          // capture K chunks for rows w*16..+16
            kreg[i] = *(const ushort4*)&cslab[(w * 16 + i) * 68 + koff];
        __syncthreads();                      // all K reads done before V overwrites
    }

    // ---- pass B (S or V) ----
    mfma_pass(acc, As, Wp, zB, w, l, q, c);
    slab_store(slab, acc, bbB, q, c);
    if (y == 0) {
        store_rows(S, slab, m0, w, l);
    } else {
        __syncthreads();                      // V slab visible
#pragma unroll
        for (int i = 0; i < 16; ++i) {
            int gr = m0 + w * 16 + i;
            ushort4 vr = *(const ushort4*)&cslab[(w * 16 + i) * 68 + koff];
            if (gr < N_NODES) {
                bf16x8 ov;
                ov[0] = (short)kreg[i].x; ov[1] = (short)kreg[i].y;
                ov[2] = (short)kreg[i].z; ov[3] = (short)kreg[i].w;
                ov[4] = (short)vr.x;      ov[5] = (short)vr.y;
                ov[6] = (short)vr.z;      ov[7] = (short)vr.w;
                *(bf16x8*)&KV[(size_t)gr * 512 + l * 8] = ov;
            }
        }
    }
}

// ---------- K2: fused attention + PD GEMM (serial-node R5 ladder, 40960 B LDS) ----------
// 512 threads = 8 waves; LDS = 40960 B -> 4 blocks/CU resource-feasible.
// launch_bounds kept (512,6): VGPR cap 85, no spill (R8 lesson).
// Wave w computes attention for rows w*8..w*8+8 (serial, 4/2/1 edge unroll for
// MLP within a node), writes the out-tile pd-swizzled into As; block then runs
// PD = out @ [W1_top|W1_bot]; PD overwrites Q (row-owner-only).
__global__ __launch_bounds__(512, 6) void attn_pd(
    const int* __restrict__ rp, const int* __restrict__ bsum,
    const int* __restrict__ deg, const int* __restrict__ csr_src,
    const unsigned short* __restrict__ Q, const unsigned short* __restrict__ KV,
    const unsigned short* __restrict__ S,
    const unsigned short* __restrict__ Wcp,
    unsigned short* __restrict__ PD)
{
    __shared__ __align__(16) short sh[8 * PSLAB];   // 40960 B: As (32768 B) + slab alias

    const int t = threadIdx.x;
    const int w = t >> 6, l = t & 63;
    const int q = l >> 4, c = l & 15;
    const int m0 = blockIdx.x * 64;
    short* As = sh;

    // node metadata for this wave's 8 nodes, gathered wave-wide once
    int meta = 0;
    {
        int nn = m0 + w * 8 + (l & 7);
        if (nn < N_NODES) {
            if (l < 8)       meta = rp[nn] + bsum[nn >> 10];
            else if (l < 16) meta = deg[nn];
        }
    }

    // ---- attention phase: wave w -> rows w*8 .. w*8+8 (serial ladder) ----
    for (int i = 0; i < 8; ++i) {
        int row  = w * 8 + i;
        int node = m0 + row;
        if (node < N_NODES) {
            int start = __shfl(meta, i);
            int cnt   = __shfl(meta, 8 + i);

            float q0, q1, q2, q3;   // pre-scaled by 1/sqrt(64)
            ushort4 su;
            {
                ushort4 u = *(const ushort4*)&Q[(size_t)node * HD + l * 4];
                su = *(const ushort4*)&S[(size_t)node * HD + l * 4];   // hoisted
                q0 = bf2f(u.x) * 0.125f; q1 = bf2f(u.y) * 0.125f;
                q2 = bf2f(u.z) * 0.125f; q3 = bf2f(u.w) * 0.125f;
            }

            float d = 0.f;
            float a0 = 0.f, a1 = 0.f, a2 = 0.f, a3 = 0.f;

            int i2 = 0;
            for (; i2 + 4 <= cnt; i2 += 4) {
                int s0 = csr_src[start + i2];
                int s1 = csr_src[start + i2 + 1];
                int s2 = csr_src[start + i2 + 2];
                int s3 = csr_src[start + i2 + 3];
                bf16x8 k0 = *(const bf16x8*)&KV[(size_t)s0 * 512 + l * 8];
                bf16x8 k1 = *(const bf16x8*)&KV[(size_t)s1 * 512 + l * 8];
                bf16x8 k2 = *(const bf16x8*)&KV[(size_t)s2 * 512 + l * 8];
                bf16x8 k3 = *(const bf16x8*)&KV[(size_t)s3 * 512 + l * 8];
                float sA = q0 * bf2f((unsigned short)k0[0]) + q1 * bf2f((unsigned short)k0[1])
                         + q2 * bf2f((unsigned short)k0[2]) + q3 * bf2f((unsigned short)k0[3]);
                float sB = q0 * bf2f((unsigned short)k1[0]) + q1 * bf2f((unsigned short)k1[1])
                         + q2 * bf2f((unsigned short)k1[2]) + q3 * bf2f((unsigned short)k1[3]);
                float sC = q0 * bf2f((unsigned short)k2[0]) + q1 * bf2f((unsigned short)k2[1])
                         + q2 * bf2f((unsigned short)k2[2]) + q3 * bf2f((unsigned short)k2[3]);
                float sD = q0 * bf2f((unsigned short)k3[0]) + q1 * bf2f((unsigned short)k3[1])
                         + q2 * bf2f((unsigned short)k3[2]) + q3 * bf2f((unsigned short)k3[3]);
                sA += __shfl_xor(sA, 1); sB += __shfl_xor(sB, 1);
                sC += __shfl_xor(sC, 1); sD += __shfl_xor(sD, 1);
                sA += __shfl_xor(sA, 2); sB += __shfl_xor(sB, 2);
                sC += __shfl_xor(sC, 2); sD += __shfl_xor(sD, 2);
                sA += __shfl_xor(sA, 4); sB += __shfl_xor(sB, 4);
                sC += __shfl_xor(sC, 4); sD += __shfl_xor(sD, 4);
                sA += __shfl_xor(sA, 8); sB += __shfl_xor(sB, 8);
                sC += __shfl_xor(sC, 8); sD += __shfl_xor(sD, 8);
                float eA = __expf(sA), eB = __expf(sB), eC = __expf(sC), eD = __expf(sD);
                d += (eA + eB) + (eC + eD);
                a0 += eA * bf2f((unsigned short)k0[4]) + eB * bf2f((unsigned short)k1[4])
                    + eC * bf2f((unsigned short)k2[4]) + eD * bf2f((unsigned short)k3[4]);
                a1 += eA * bf2f((unsigned short)k0[5]) + eB * bf2f((unsigned short)k1[5])
                    + eC * bf2f((unsigned short)k2[5]) + eD * bf2f((unsigned short)k3[5]);
                a2 += eA * bf2f((unsigned short)k0[6]) + eB * bf2f((unsigned short)k1[6])
                    + eC * bf2f((unsigned short)k2[6]) + eD * bf2f((unsigned short)k3[6]);
                a3 += eA * bf2f((unsigned short)k0[7]) + eB * bf2f((unsigned short)k1[7])
                    + eC * bf2f((unsigned short)k2[7]) + eD * bf2f((unsigned short)k3[7]);
            }
            if (i2 + 2 <= cnt) {
                int s0 = csr_src[start + i2];
                int s1 = csr_src[start + i2 + 1];
                bf16x8 k0 = *(const bf16x8*)&KV[(size_t)s0 * 512 + l * 8];
                bf16x8 k1 = *(const bf16x8*)&KV[(size_t)s1 * 512 + l * 8];
                float sA = q0 * bf2f((unsigned short)k0[0]) + q1 * bf2f((unsigned short)k0[1])
                         + q2 * bf2f((unsigned short)k0[2]) + q3 * bf2f((unsigned short)k0[3]);
                float sB = q0 * bf2f((unsigned short)k1[0]) + q1 * bf2f((unsigned short)k1[1])
                         + q2 * bf2f((unsigned short)k1[2]) + q3 * bf2f((unsigned short)k1[3]);
                sA += __shfl_xor(sA, 1); sB += __shfl_xor(sB, 1);
                sA += __shfl_xor(sA, 2); sB += __shfl_xor(sB, 2);
                sA += __shfl_xor(sA, 4); sB += __shfl_xor(sB, 4);
                sA += __shfl_xor(sA, 8); sB += __shfl_xor(sB, 8);
                float eA = __expf(sA), eB = __expf(sB);
                d += eA + eB;
                a0 += eA * bf2f((unsigned short)k0[4]) + eB * bf2f((unsigned short)k1[4]);
                a1 += eA * bf2f((unsigned short)k0[5]) + eB * bf2f((unsigned short)k1[5]);
                a2 += eA * bf2f((unsigned short)k0[6]) + eB * bf2f((unsigned short)k1[6]);
                a3 += eA * bf2f((unsigned short)k0[7]) + eB * bf2f((unsigned short)k1[7]);
                i2 += 2;
            }
            if (i2 < cnt) {
                int s0 = csr_src[start + i2];
                bf16x8 k0 = *(const bf16x8*)&KV[(size_t)s0 * 512 + l * 8];
                float sA = q0 * bf2f((unsigned short)k0[0]) + q1 * bf2f((unsigned short)k0[1])
                         + q2 * bf2f((unsigned short)k0[2]) + q3 * bf2f((unsigned short)k0[3]);
                sA += __shfl_xor(sA, 1);
                sA += __shfl_xor(sA, 2);
                sA += __shfl_xor(sA, 4);
                sA += __shfl_xor(sA, 8);
                float eA = __expf(sA);
                d += eA;
                a0 += eA * bf2f((unsigned short)k0[4]);
                a1 += eA * bf2f((unsigned short)k0[5]);
                a2 += eA * bf2f((unsigned short)k0[6]);
                a3 += eA * bf2f((unsigned short)k0[7]);
            }

            float inv = 1.f / (d + 1e-16f);
            ushort4 ov = make_ushort4(fbf(bf2f(su.x) + a0 * inv),
                                      fbf(bf2f(su.y) + a1 * inv),
                                      fbf(bf2f(su.z) + a2 * inv),
                                      fbf(bf2f(su.w) + a3 * inv));
            // write into PD A-tile, pd-swizzled: logical 16B-chunk lc=l>>1 of row
            // stored at physical chunk lc^(row&7), half (l&1)
            *(ushort4*)&As[row * 256 + (((l >> 1) ^ (row & 7)) << 3) + ((l & 1) << 2)] = ov;
        }
    }
    __syncthreads();   // out-tile complete

    // ---- PD GEMM phase: 8 waves x 2 N-tiles, K=256 ----
    f32x4 acc[4][2];
#pragma unroll
    for (int mt = 0; mt < 4; ++mt)
#pragma unroll
        for (int nt = 0; nt < 2; ++nt) acc[mt][nt] = (f32x4){0.f, 0.f, 0.f, 0.f};

#pragma unroll
    for (int kt = 0; kt < 8; ++kt) {
        bf16x8 af[4];
#pragma unroll
        for (int mt = 0; mt < 4; ++mt) {
            int row  = mt * 16 + c;
            int slot = (kt * 4 + q) ^ (row & 7);
            af[mt] = *(const bf16x8*)&As[row * 256 + slot * 8];
        }
#pragma unroll
        for (int nt = 0; nt < 2; ++nt) {
            int ntg = w * 2 + nt;
            bf16x8 bv8 = *(const bf16x8*)&Wcp[(size_t)((kt * 16 + ntg) * 64 + l) * 8];
#pragma unroll
            for (int mt = 0; mt < 4; ++mt)
                acc[mt][nt] = __builtin_amdgcn_mfma_f32_16x16x32_bf16(af[mt], bv8, acc[mt][nt], 0, 0, 0);
        }
    }
    __syncthreads();   // all As reads done; slab regions alias As

    short* slab = &sh[w * PSLAB];   // [64][40], cols w*32..w*32+32
#pragma unroll
    for (int nt = 0; nt < 2; ++nt)
#pragma unroll
        for (int mt = 0; mt < 4; ++mt)
#pragma unroll
            for (int r = 0; r < 4; ++r)
                slab[(mt * 16 + q * 4 + r) * 40 + nt * 16 + c] =
                    (short)fbf(acc[mt][nt][r]);
    __syncthreads();   // slabs visible cross-wave

    // store: wave w stores rows w*8..w*8+8; lane l -> col-chunk cc=l&31 (8 cols)
    const int cc = l & 31;
    const short* sb = &sh[(cc >> 2) * PSLAB + (cc & 3) * 8];
#pragma unroll
    for (int i = 0; i < 4; ++i) {
        int row = w * 8 + i * 2 + (l >> 5);
        int gr  = m0 + row;
        if (gr < N_NODES)
            *(bf16x8*)&PD[(size_t)gr * HD + cc * 8] = *(const bf16x8*)&sb[row * 40];
    }
}

// ---------- K5: light edge MLP — h1 = relu(P[src]+D[dst]+b1); layer2 MFMA; layer3 ----------
__global__ __launch_bounds__(256) void edge_mlp_pd(
    const int* __restrict__ csr_src, const int* __restrict__ csr_dst,
    const int* __restrict__ csr_eid,
    const unsigned short* __restrict__ PD,
    const float* __restrict__ b1,
    const unsigned short* __restrict__ W2p, const float* __restrict__ b2,
    const float* __restrict__ W3, const float* __restrict__ b3,
    float* __restrict__ rating)
{
    __shared__ __align__(16) char lds[64 * 136 * 2];   // 17408 B union:
    short* h1t = (short*)lds;                          //   h1 bf16 [64][136]
    float* h2s = (float*)lds;                          //   h2 f32 [64][65] (aliases after barrier)

    const int t = threadIdx.x;
    const int w = t >> 6, l = t & 63;
    const int q = l >> 4, c = l & 15;
    const int e0 = blockIdx.x * 64;

    // stage h1 = relu(P[src] + D[dst] + b1): 64 rows x 128 cols bf16
#pragma unroll
    for (int j = 0; j < 4; ++j) {
        int idx = t + j * 256;          // 1024 chunks of 8 elems
        int row = idx >> 4, ch = idx & 15;
        int src = csr_src[e0 + row];
        int dst = csr_dst[e0 + row];
        bf16x8 pv = *(const bf16x8*)&PD[(size_t)src * HD + ch * 8];
        bf16x8 dv = *(const bf16x8*)&PD[(size_t)dst * HD + 128 + ch * 8];
        float4 ba = *(const float4*)&b1[ch * 8];
        float4 bb = *(const float4*)&b1[ch * 8 + 4];
        bf16x8 hv;
        hv[0] = (short)fbf(fmaxf(bf2f((unsigned short)pv[0]) + bf2f((unsigned short)dv[0]) + ba.x, 0.f));
        hv[1] = (short)fbf(fmaxf(bf2f((unsigned short)pv[1]) + bf2f((unsigned short)dv[1]) + ba.y, 0.f));
        hv[2] = (short)fbf(fmaxf(bf2f((unsigned short)pv[2]) + bf2f((unsigned short)dv[2]) + ba.z, 0.f));
        hv[3] = (short)fbf(fmaxf(bf2f((unsigned short)pv[3]) + bf2f((unsigned short)dv[3]) + ba.w, 0.f));
        hv[4] = (short)fbf(fmaxf(bf2f((unsigned short)pv[4]) + bf2f((unsigned short)dv[4]) + bb.x, 0.f));
        hv[5] = (short)fbf(fmaxf(bf2f((unsigned short)pv[5]) + bf2f((unsigned short)dv[5]) + bb.y, 0.f));
        hv[6] = (short)fbf(fmaxf(bf2f((unsigned short)pv[6]) + bf2f((unsigned short)dv[6]) + bb.z, 0.f));
        hv[7] = (short)fbf(fmaxf(bf2f((unsigned short)pv[7]) + bf2f((unsigned short)dv[7]) + bb.w, 0.f));
        *(bf16x8*)&h1t[row * 136 + ch * 8] = hv;
    }
    __syncthreads();

    // layer2 MFMA: [64,128] @ [128,64]
    f32x4 acc2[4];
#pragma unroll
    for (int i = 0; i < 4; ++i) acc2[i] = (f32x4){0.f, 0.f, 0.f, 0.f};
#pragma unroll
    for (int kt = 0; kt < 4; ++kt) {
        bf16x8 av = *(const bf16x8*)&h1t[(w * 16 + c) * 136 + kt * 32 + q * 8];
#pragma unroll
        for (int nt = 0; nt < 4; ++nt) {
            bf16x8 bv = *(const bf16x8*)&W2p[(size_t)((kt * 4 + nt) * 64 + l) * 8];
            acc2[nt] = __builtin_amdgcn_mfma_f32_16x16x32_bf16(av, bv, acc2[nt], 0, 0, 0);
        }
    }
    __syncthreads();   // h1 reads done; h2 aliases

#pragma unroll
    for (int nt = 0; nt < 4; ++nt) {
        float bv = b2[nt * 16 + c];
#pragma unroll
        for (int r = 0; r < 4; ++r)
            h2s[(w * 16 + q * 4 + r) * 65 + nt * 16 + c] = fmaxf(acc2[nt][r] + bv, 0.f);
    }
    __syncthreads();

    // layer3: all 256 threads — 4 partials per edge + shfl reduce
    {
        int e = t >> 2, part = t & 3;
        float a = 0.f;
#pragma unroll
        for (int kk = 0; kk < 16; ++kk)
            a += h2s[e * 65 + part * 16 + kk] * W3[part * 16 + kk];
        a += __shfl_xor(a, 1);
        a += __shfl_xor(a, 2);
        if (part == 0)
            rating[csr_eid[e0 + e]] = 4.f / (1.f + __expf(-(a + b3[0]))) + 1.f;
    }
}

extern "C" void kernel_launch(void* const* d_in, const int* in_sizes, int n_in,
                              void* d_out, int out_size, void* d_ws, size_t ws_size,
                              hipStream_t stream) {
    const int*   ei  = (const int*)d_in[0];    // [2, E]
    const float* x   = (const float*)d_in[2];
    const float* mem = (const float*)d_in[3];
    const float* Wq  = (const float*)d_in[4];
    const float* bq  = (const float*)d_in[5];
    const float* Wk  = (const float*)d_in[6];
    const float* bk  = (const float*)d_in[7];
    const float* Wv  = (const float*)d_in[8];
    const float* bv  = (const float*)d_in[9];
    const float* Ws  = (const float*)d_in[10];
    const float* bs  = (const float*)d_in[11];
    const float* W1  = (const float*)d_in[12];
    const float* b1  = (const float*)d_in[13];
    const float* W2  = (const float*)d_in[14];
    const float* b2  = (const float*)d_in[15];
    const float* W3  = (const float*)d_in[16];
    const float* b3  = (const float*)d_in[17];
    float* rating = (float*)d_out;

    // Workspace (~237 MB):
    //   Q  [N,256] bf16 (PD aliases Q after attn_pd)          51.2 MB
    //   KV [N,512] bf16 (lane-interleaved K|V)               102.4 MB
    //   S  [N,256] bf16                                       51.2 MB
    //   H  [N,128] bf16 (x+mem)                               25.6 MB
    //   rp, deg, cursor, csr_*, bsum, packs                   ~6.8 MB
    unsigned short* Q = (unsigned short*)d_ws;
    const size_t NHDe = (size_t)N_NODES * HD;   // 25.6M elements
    unsigned short* KV = Q + NHDe;              // N*512 elements
    unsigned short* S  = KV + 2 * NHDe;
    unsigned short* H  = S + NHDe;              // N*128 elements
    int* rp      = (int*)(H + (size_t)N_NODES * HID);
    int* deg     = rp + N_NODES;
    int* cursor  = deg + N_NODES;
    int* csr_src = cursor + N_NODES;
    int* csr_dst = csr_src + N_EDGES;
    int* csr_eid = csr_dst + N_EDGES;
    int* bsum    = csr_eid + N_EDGES;
    unsigned short* Wp  = (unsigned short*)(bsum + 128);
    unsigned short* Wcp = Wp + 16384 * 8;
    unsigned short* W2p = Wcp + 8192 * 8;
    unsigned short* PD  = Q;   // attn_pd writes PD in place of Q (row-owner-only)

    const int eblk  = (N_EDGES + 255) / 256;
    const int pblk  = (N_NODES * HID / 8 + 255) / 256;   // 6250
    const int gblk  = (N_NODES + 63) / 64;               // 1563

    // CSR build + weight packing (deg and cursor are adjacent -> one memset)
    hipMemsetAsync(deg, 0, sizeof(int) * 2 * N_NODES, stream);
    k_deg<<<eblk, 256, 0, stream>>>(ei, deg);
    k_scan1<<<NB_SCAN, 256, 0, stream>>>(deg, rp, bsum);
    k_scan2<<<1, 256, 0, stream>>>(bsum);
    k_bucket<<<eblk, 256, 0, stream>>>(ei, rp, bsum, cursor, csr_src, csr_dst, csr_eid);
    pack_all<<<100, 256, 0, stream>>>(Wq, Wk, Wv, Ws, W1, W2, Wp, Wcp, W2p);

    // H = bf16(x + mem), one streaming pass
    k_pre<<<pblk, 256, 0, stream>>>(x, mem, H);

    // projections: y=0 -> Q,S ; y=1 -> K,V (merged interleaved store)
    gemm4<<<dim3(gblk, 2), dim3(256), 0, stream>>>(
        H, Wp, bq, bk, bv, bs, Q, KV, S);

    // fused attention + PD GEMM (serial ladder; PD overwrites Q)
    attn_pd<<<gblk, 512, 0, stream>>>(rp, bsum, deg, csr_src, Q, KV, S, Wcp, PD);

    // light edge MLP in CSR order
    edge_mlp_pd<<<N_EDGES / 64, 256, 0, stream>>>(
        csr_src, csr_dst, csr_eid, PD, b1, W2p, b2, W3, b3, rating);
}

// Round 11
// 415.852 us; speedup vs baseline: 1.4389x; 1.0062x over previous
//
#include <hip/hip_runtime.h>
#include <math.h>

#define N_NODES 100000
#define N_EDGES 400000
#define HID 128
#define HEADS 4
#define OUT_C 64
#define HD 256   // HEADS*OUT_C
#define SCAN_CHUNK 1024
#define NB_SCAN ((N_NODES + SCAN_CHUNK - 1) / SCAN_CHUNK)   // 98
#define SLAB2 2176   // gemm4 per-wave HALF-slab stride (32*68 ushorts; stride 68 = conflict-free)
#define PSLAB 2560   // attn_pd slab region stride (ushorts; 64*40 -> 40960 B total)

typedef __attribute__((ext_vector_type(8))) short bf16x8;   // 8 bf16 = 4 VGPRs
typedef __attribute__((ext_vector_type(4))) float f32x4;

// fp32 -> bf16 round-to-nearest-even
__device__ __forceinline__ unsigned short fbf(float f) {
    unsigned u = __float_as_uint(f);
    unsigned r = (u + 0x7fffu + ((u >> 16) & 1u)) >> 16;
    return (unsigned short)r;
}
__device__ __forceinline__ float bf2f(unsigned short u) {
    return __uint_as_float(((unsigned)u) << 16);
}

// async global->LDS, 16B per lane; LDS dest = wave-uniform base + lane*16
__device__ __forceinline__ void gl_lds16(const void* g, void* l) {
    __builtin_amdgcn_global_load_lds(
        (const __attribute__((address_space(1))) unsigned int*)g,
        (__attribute__((address_space(3))) unsigned int*)l,
        16, 0, 0);
}

// ---------- CSR build: degree count ----------
__global__ __launch_bounds__(256) void k_deg(const int* __restrict__ ei,
                                             int* __restrict__ deg) {
    int e = blockIdx.x * 256 + threadIdx.x;
    if (e < N_EDGES) atomicAdd(&deg[ei[N_EDGES + e]], 1);
}

// ---------- scan 1 ----------
__global__ __launch_bounds__(256) void k_scan1(const int* __restrict__ deg,
                                               int* __restrict__ rp,
                                               int* __restrict__ bsum) {
    __shared__ int ts[256];
    int b = blockIdx.x, t = threadIdx.x;
    int base = b * SCAN_CHUNK + t * 4;
    int vv[4];
    int s = 0;
#pragma unroll
    for (int i = 0; i < 4; ++i) {
        int d = (base + i < N_NODES) ? deg[base + i] : 0;
        vv[i] = s;
        s += d;
    }
    ts[t] = s;
    __syncthreads();
    for (int off = 1; off < 256; off <<= 1) {
        int x = (t >= off) ? ts[t - off] : 0;
        __syncthreads();
        ts[t] += x;
        __syncthreads();
    }
    int ex = ts[t] - s;
#pragma unroll
    for (int i = 0; i < 4; ++i)
        if (base + i < N_NODES) rp[base + i] = ex + vv[i];
    if (t == 255) bsum[b] = ts[255];
}

// ---------- scan 2 ----------
__global__ __launch_bounds__(256) void k_scan2(int* __restrict__ bsum) {
    __shared__ int ts[256];
    int t = threadIdx.x;
    int v = (t < NB_SCAN) ? bsum[t] : 0;
    ts[t] = v;
    __syncthreads();
    for (int off = 1; off < 256; off <<= 1) {
        int x = (t >= off) ? ts[t - off] : 0;
        __syncthreads();
        ts[t] += x;
        __syncthreads();
    }
    if (t < NB_SCAN) bsum[t] = ts[t] - v;
}

// ---------- bucket: fill csr_src / csr_dst / csr_eid (rp finalized inline via bsum) ----------
__global__ __launch_bounds__(256) void k_bucket(const int* __restrict__ ei,
                                                const int* __restrict__ rp,
                                                const int* __restrict__ bsum,
                                                int* __restrict__ cursor,
                                                int* __restrict__ csr_src,
                                                int* __restrict__ csr_dst,
                                                int* __restrict__ csr_eid) {
    int e = blockIdx.x * 256 + threadIdx.x;
    if (e >= N_EDGES) return;
    int src = ei[e];
    int d   = ei[N_EDGES + e];
    int idx = atomicAdd(&cursor[d], 1);
    int s   = rp[d] + bsum[d >> 10] + idx;
    csr_src[s] = src;
    csr_dst[s] = d;
    csr_eid[s] = e;
}

// ---------- merged weight packing ----------
__global__ __launch_bounds__(256) void pack_all(
    const float* __restrict__ Wq, const float* __restrict__ Wk,
    const float* __restrict__ Wv, const float* __restrict__ Ws,
    const float* __restrict__ W1, const float* __restrict__ W2,
    unsigned short* __restrict__ Wp, unsigned short* __restrict__ Wcp,
    unsigned short* __restrict__ W2p) {
    int i = blockIdx.x * 256 + threadIdx.x;   // 25600 total
    int lane = i & 63;
    int q = lane >> 4, c = lane & 15;
    if (i < 16384) {
        int nt = (i >> 6) & 15, kt = (i >> 10) & 3, z = i >> 12;
        const float* W = (z == 0) ? Wq : (z == 1) ? Wk : (z == 2) ? Wv : Ws;
#pragma unroll
        for (int j = 0; j < 8; ++j)
            Wp[i * 8 + j] = fbf(W[(kt * 32 + q * 8 + j) * HD + nt * 16 + c]);
    } else if (i < 24576) {
        int ii = i - 16384;
        int nt = (ii >> 6) & 15, kt = ii >> 10;
        int n = nt * 16 + c;
#pragma unroll
        for (int j = 0; j < 8; ++j) {
            int k = kt * 32 + q * 8 + j;
            float v = (n < 128) ? W1[k * 128 + n] : W1[(k + 256) * 128 + (n - 128)];
            Wcp[ii * 8 + j] = fbf(v);
        }
    } else if (i < 25600) {
        int ii = i - 24576;
        int nt = (ii >> 6) & 3, kt = ii >> 8;
#pragma unroll
        for (int j = 0; j < 8; ++j)
            W2p[ii * 8 + j] = fbf(W2[(kt * 32 + q * 8 + j) * 64 + nt * 16 + c]);
    }
}

// ---------- K_pre: H = bf16(x + mem), one streaming pass ----------
__global__ __launch_bounds__(256) void k_pre(const float* __restrict__ x,
                                             const float* __restrict__ mem,
                                             unsigned short* __restrict__ H) {
    int idx = blockIdx.x * 256 + threadIdx.x;      // chunk of 8 elems
    if (idx >= N_NODES * HID / 8) return;          // 1,600,000 chunks
    const float4* x4 = (const float4*)x;
    const float4* m4 = (const float4*)mem;
    float4 a0 = x4[(size_t)idx * 2],     a1 = x4[(size_t)idx * 2 + 1];
    float4 b0 = m4[(size_t)idx * 2],     b1 = m4[(size_t)idx * 2 + 1];
    bf16x8 hv;
    hv[0] = (short)fbf(a0.x + b0.x); hv[1] = (short)fbf(a0.y + b0.y);
    hv[2] = (short)fbf(a0.z + b0.z); hv[3] = (short)fbf(a0.w + b0.w);
    hv[4] = (short)fbf(a1.x + b1.x); hv[5] = (short)fbf(a1.y + b1.y);
    hv[6] = (short)fbf(a1.z + b1.z); hv[7] = (short)fbf(a1.w + b1.w);
    *(bf16x8*)&H[(size_t)idx * 8] = hv;
}

// ---------- gemm4 MFMA pass helper ----------
__device__ __forceinline__ void mfma_pass(f32x4 acc[4][4], const short* As,
        const unsigned short* __restrict__ Wp, int z, int w, int l, int q, int c) {
#pragma unroll
    for (int mt = 0; mt < 4; ++mt)
#pragma unroll
        for (int nt = 0; nt < 4; ++nt) acc[mt][nt] = (f32x4){0.f, 0.f, 0.f, 0.f};
#pragma unroll
    for (int kt = 0; kt < 4; ++kt) {
        bf16x8 af[4];
#pragma unroll
        for (int mt = 0; mt < 4; ++mt) {
            int row  = mt * 16 + c;
            int slot = (kt * 4 + q) ^ (row & 7);
            af[mt] = *(const bf16x8*)&As[row * 128 + slot * 8];
        }
#pragma unroll
        for (int nt = 0; nt < 4; ++nt) {
            bf16x8 bw8 = *(const bf16x8*)&Wp[(size_t)(((z * 4 + kt) * 16 + w * 4 + nt) * 64 + l) * 8];
#pragma unroll
            for (int mt = 0; mt < 4; ++mt)
                acc[mt][nt] = __builtin_amdgcn_mfma_f32_16x16x32_bf16(af[mt], bw8, acc[mt][nt], 0, 0, 0);
        }
    }
}

// store half h (output rows h*32..h*32+32) of acc into the wave's [32][68] slab
__device__ __forceinline__ void slab_half(short* slab, const f32x4 acc[4][4],
        const float bb[4], int h, int q, int c) {
#pragma unroll
    for (int mtl = 0; mtl < 2; ++mtl) {
        int mt = h * 2 + mtl;
#pragma unroll
        for (int nt = 0; nt < 4; ++nt)
#pragma unroll
            for (int r = 0; r < 4; ++r)
                slab[(mtl * 16 + q * 4 + r) * 68 + nt * 16 + c] =
                    (short)fbf(acc[mt][nt][r] + bb[nt]);
    }
}

// ---------- K1: projection GEMM, 2-way y split, HALF-slab ----------
// LDS = 16384 (As) + 17408 (4x[32][68]) = 33792 B -> 4 blocks/CU.
// launch_bounds stays (256,3): VGPR cap ~170 (compiler uses ~84, NO spill —
// R8's regression was the (256,4) 64-VGPR cap + stride-66 bank conflicts).
// y=0: Q pass then S pass (wave-private slab halves, no barriers)
// y=1: K then V; per-half cross-wave capture; merged lane-interleaved KV store
__global__ __launch_bounds__(256, 3) void gemm4(
    const unsigned short* __restrict__ H,
    const unsigned short* __restrict__ Wp,
    const float* __restrict__ bq, const float* __restrict__ bk,
    const float* __restrict__ bv, const float* __restrict__ bs,
    unsigned short* __restrict__ Q, unsigned short* __restrict__ KV,
    unsigned short* __restrict__ S)
{
    __shared__ __align__(16) short As[64 * 128];      // 16384 B, lives across both passes
    __shared__ __align__(16) short Slab[4 * SLAB2];   // 17408 B (4 x [32][68])

    const int t = threadIdx.x;
    const int w = t >> 6, l = t & 63;
    const int q = l >> 4, c = l & 15;
    const int y  = blockIdx.y;          // 0: Q,S   1: K,V
    const int m0 = blockIdx.x * 64;

    // async stage H tile 64x128 bf16: linear LDS dest, XOR-pre-swizzled global src
#pragma unroll
    for (int i = 0; i < 4; ++i) {
        int rbase = w * 16 + i * 4;
        int r  = rbase + (l >> 4);
        int gr = m0 + r; if (gr >= N_NODES) gr = N_NODES - 1;   // clamp; stores guarded
        int ks = (l & 15) ^ (r & 7);
        gl_lds16(&H[(size_t)gr * HID + ks * 8], &As[rbase * 128]);
    }

    const int   zA  = (y == 0) ? 0 : 1;
    const int   zB  = (y == 0) ? 3 : 2;
    const float* bA = (y == 0) ? bq : bk;
    const float* bB = (y == 0) ? bs : bv;
    float bbA[4], bbB[4];
#pragma unroll
    for (int nt = 0; nt < 4; ++nt) {
        bbA[nt] = bA[w * 64 + nt * 16 + c];
        bbB[nt] = bB[w * 64 + nt * 16 + c];
    }

    __syncthreads();   // As ready

    short* slab = &Slab[w * SLAB2];
    f32x4 acc[4][4];
    ushort4 kreg[16];
    const int koff  = (l & 15) * 4;
    const short* cslab = &Slab[(l >> 4) * SLAB2];   // cross-wave chunk source
    const int hw = w >> 1;          // half containing this wave's 16 KV output rows
    const int lw = (w & 1) * 16;    // local row base within that half
    const int srow = l >> 3, schk = l & 7;

    // ---- pass A (Q or K) ----
    mfma_pass(acc, As, Wp, zA, w, l, q, c);
    if (y == 0) {
#pragma unroll
        for (int h = 0; h < 2; ++h) {
            slab_half(slab, acc, bbA, h, q, c);     // own-wave region
#pragma unroll
            for (int j = 0; j < 4; ++j) {           // read back own region: no barrier
                int lr = j * 8 + srow;
                int gr = m0 + h * 32 + lr;
                if (gr < N_NODES)
                    *(bf16x8*)&Q[(size_t)gr * HD + w * 64 + schk * 8] =
                        *(const bf16x8*)&slab[lr * 68 + schk * 8];
            }
        }
    } else {
#pragma unroll
        for (int h = 0; h < 2; ++h) {
            slab_half(slab, acc, bbA, h, q, c);
            __syncthreads();                        // K half visible to all waves
            if (hw == h) {
#pragma unroll
                for (int i = 0; i < 16; ++i)        // capture K chunks for rows w*16..+16
                    kreg[i] = *(const ushort4*)&cslab[(lw + i) * 68 + koff];
            }
            __syncthreads();                        // captures done before overwrite
        }
    }

    // ---- pass B (S or V) ----
    mfma_pass(acc, As, Wp, zB, w, l, q, c);
    if (y == 0) {
#pragma unroll
        for (int h = 0; h < 2; ++h) {
            slab_half(slab, acc, bbB, h, q, c);
#pragma unroll
            for (int j = 0; j < 4; ++j) {
                int lr = j * 8 + srow;
                int gr = m0 + h * 32 + lr;
                if (gr < N_NODES)
                    *(bf16x8*)&S[(size_t)gr * HD + w * 64 + schk * 8] =
                        *(const bf16x8*)&slab[lr * 68 + schk * 8];
            }
        }
    } else {
#pragma unroll
        for (int h = 0; h < 2; ++h) {
            slab_half(slab, acc, bbB, h, q, c);
            __syncthreads();                        // V half visible
            if (hw == h) {
#pragma unroll
                for (int i = 0; i < 16; ++i) {
                    int gr = m0 + w * 16 + i;
                    ushort4 vr = *(const ushort4*)&cslab[(lw + i) * 68 + koff];
                    if (gr < N_NODES) {
                        bf16x8 ov;
                        ov[0] = (short)kreg[i].x; ov[1] = (short)kreg[i].y;
                        ov[2] = (short)kreg[i].z; ov[3] = (short)kreg[i].w;
                        ov[4] = (short)vr.x;      ov[5] = (short)vr.y;
                        ov[6] = (short)vr.z;      ov[7] = (short)vr.w;
                        *(bf16x8*)&KV[(size_t)gr * 512 + l * 8] = ov;
                    }
                }
            }
            __syncthreads();                        // before next half overwrites
        }
    }
}

// ---------- K2: fused attention + PD GEMM (serial ladder, 40960 B LDS) ----------
// Proven 104 us (R10); occupancy floor is structural, not LDS (R10 falsifier).
__global__ __launch_bounds__(512, 6) void attn_pd(
    const int* __restrict__ rp, const int* __restrict__ bsum,
    const int* __restrict__ deg, const int* __restrict__ csr_src,
    const unsigned short* __restrict__ Q, const unsigned short* __restrict__ KV,
    const unsigned short* __restrict__ S,
    const unsigned short* __restrict__ Wcp,
    unsigned short* __restrict__ PD)
{
    __shared__ __align__(16) short sh[8 * PSLAB];   // 40960 B: As (32768 B) + slab alias

    const int t = threadIdx.x;
    const int w = t >> 6, l = t & 63;
    const int q = l >> 4, c = l & 15;
    const int m0 = blockIdx.x * 64;
    short* As = sh;

    // node metadata for this wave's 8 nodes, gathered wave-wide once
    int meta = 0;
    {
        int nn = m0 + w * 8 + (l & 7);
        if (nn < N_NODES) {
            if (l < 8)       meta = rp[nn] + bsum[nn >> 10];
            else if (l < 16) meta = deg[nn];
        }
    }

    // ---- attention phase: wave w -> rows w*8 .. w*8+8 (serial ladder) ----
    for (int i = 0; i < 8; ++i) {
        int row  = w * 8 + i;
        int node = m0 + row;
        if (node < N_NODES) {
            int start = __shfl(meta, i);
            int cnt   = __shfl(meta, 8 + i);

            float q0, q1, q2, q3;   // pre-scaled by 1/sqrt(64)
            ushort4 su;
            {
                ushort4 u = *(const ushort4*)&Q[(size_t)node * HD + l * 4];
                su = *(const ushort4*)&S[(size_t)node * HD + l * 4];   // hoisted
                q0 = bf2f(u.x) * 0.125f; q1 = bf2f(u.y) * 0.125f;
                q2 = bf2f(u.z) * 0.125f; q3 = bf2f(u.w) * 0.125f;
            }

            float d = 0.f;
            float a0 = 0.f, a1 = 0.f, a2 = 0.f, a3 = 0.f;

            int i2 = 0;
            for (; i2 + 4 <= cnt; i2 += 4) {
                int s0 = csr_src[start + i2];
                int s1 = csr_src[start + i2 + 1];
                int s2 = csr_src[start + i2 + 2];
                int s3 = csr_src[start + i2 + 3];
                bf16x8 k0 = *(const bf16x8*)&KV[(size_t)s0 * 512 + l * 8];
                bf16x8 k1 = *(const bf16x8*)&KV[(size_t)s1 * 512 + l * 8];
                bf16x8 k2 = *(const bf16x8*)&KV[(size_t)s2 * 512 + l * 8];
                bf16x8 k3 = *(const bf16x8*)&KV[(size_t)s3 * 512 + l * 8];
                float sA = q0 * bf2f((unsigned short)k0[0]) + q1 * bf2f((unsigned short)k0[1])
                         + q2 * bf2f((unsigned short)k0[2]) + q3 * bf2f((unsigned short)k0[3]);
                float sB = q0 * bf2f((unsigned short)k1[0]) + q1 * bf2f((unsigned short)k1[1])
                         + q2 * bf2f((unsigned short)k1[2]) + q3 * bf2f((unsigned short)k1[3]);
                float sC = q0 * bf2f((unsigned short)k2[0]) + q1 * bf2f((unsigned short)k2[1])
                         + q2 * bf2f((unsigned short)k2[2]) + q3 * bf2f((unsigned short)k2[3]);
                float sD = q0 * bf2f((unsigned short)k3[0]) + q1 * bf2f((unsigned short)k3[1])
                         + q2 * bf2f((unsigned short)k3[2]) + q3 * bf2f((unsigned short)k3[3]);
                sA += __shfl_xor(sA, 1); sB += __shfl_xor(sB, 1);
                sC += __shfl_xor(sC, 1); sD += __shfl_xor(sD, 1);
                sA += __shfl_xor(sA, 2); sB += __shfl_xor(sB, 2);
                sC += __shfl_xor(sC, 2); sD += __shfl_xor(sD, 2);
                sA += __shfl_xor(sA, 4); sB += __shfl_xor(sB, 4);
                sC += __shfl_xor(sC, 4); sD += __shfl_xor(sD, 4);
                sA += __shfl_xor(sA, 8); sB += __shfl_xor(sB, 8);
                sC += __shfl_xor(sC, 8); sD += __shfl_xor(sD, 8);
                float eA = __expf(sA), eB = __expf(sB), eC = __expf(sC), eD = __expf(sD);
                d += (eA + eB) + (eC + eD);
                a0 += eA * bf2f((unsigned short)k0[4]) + eB * bf2f((unsigned short)k1[4])
                    + eC * bf2f((unsigned short)k2[4]) + eD * bf2f((unsigned short)k3[4]);
                a1 += eA * bf2f((unsigned short)k0[5]) + eB * bf2f((unsigned short)k1[5])
                    + eC * bf2f((unsigned short)k2[5]) + eD * bf2f((unsigned short)k3[5]);
                a2 += eA * bf2f((unsigned short)k0[6]) + eB * bf2f((unsigned short)k1[6])
                    + eC * bf2f((unsigned short)k2[6]) + eD * bf2f((unsigned short)k3[6]);
                a3 += eA * bf2f((unsigned short)k0[7]) + eB * bf2f((unsigned short)k1[7])
                    + eC * bf2f((unsigned short)k2[7]) + eD * bf2f((unsigned short)k3[7]);
            }
            if (i2 + 2 <= cnt) {
                int s0 = csr_src[start + i2];
                int s1 = csr_src[start + i2 + 1];
                bf16x8 k0 = *(const bf16x8*)&KV[(size_t)s0 * 512 + l * 8];
                bf16x8 k1 = *(const bf16x8*)&KV[(size_t)s1 * 512 + l * 8];
                float sA = q0 * bf2f((unsigned short)k0[0]) + q1 * bf2f((unsigned short)k0[1])
                         + q2 * bf2f((unsigned short)k0[2]) + q3 * bf2f((unsigned short)k0[3]);
                float sB = q0 * bf2f((unsigned short)k1[0]) + q1 * bf2f((unsigned short)k1[1])
                         + q2 * bf2f((unsigned short)k1[2]) + q3 * bf2f((unsigned short)k1[3]);
                sA += __shfl_xor(sA, 1); sB += __shfl_xor(sB, 1);
                sA += __shfl_xor(sA, 2); sB += __shfl_xor(sB, 2);
                sA += __shfl_xor(sA, 4); sB += __shfl_xor(sB, 4);
                sA += __shfl_xor(sA, 8); sB += __shfl_xor(sB, 8);
                float eA = __expf(sA), eB = __expf(sB);
                d += eA + eB;
                a0 += eA * bf2f((unsigned short)k0[4]) + eB * bf2f((unsigned short)k1[4]);
                a1 += eA * bf2f((unsigned short)k0[5]) + eB * bf2f((unsigned short)k1[5]);
                a2 += eA * bf2f((unsigned short)k0[6]) + eB * bf2f((unsigned short)k1[6]);
                a3 += eA * bf2f((unsigned short)k0[7]) + eB * bf2f((unsigned short)k1[7]);
                i2 += 2;
            }
            if (i2 < cnt) {
                int s0 = csr_src[start + i2];
                bf16x8 k0 = *(const bf16x8*)&KV[(size_t)s0 * 512 + l * 8];
                float sA = q0 * bf2f((unsigned short)k0[0]) + q1 * bf2f((unsigned short)k0[1])
                         + q2 * bf2f((unsigned short)k0[2]) + q3 * bf2f((unsigned short)k0[3]);
                sA += __shfl_xor(sA, 1);
                sA += __shfl_xor(sA, 2);
                sA += __shfl_xor(sA, 4);
                sA += __shfl_xor(sA, 8);
                float eA = __expf(sA);
                d += eA;
                a0 += eA * bf2f((unsigned short)k0[4]);
                a1 += eA * bf2f((unsigned short)k0[5]);
                a2 += eA * bf2f((unsigned short)k0[6]);
                a3 += eA * bf2f((unsigned short)k0[7]);
            }

            float inv = 1.f / (d + 1e-16f);
            ushort4 ov = make_ushort4(fbf(bf2f(su.x) + a0 * inv),
                                      fbf(bf2f(su.y) + a1 * inv),
                                      fbf(bf2f(su.z) + a2 * inv),
                                      fbf(bf2f(su.w) + a3 * inv));
            // write into PD A-tile, pd-swizzled: logical 16B-chunk lc=l>>1 of row
            // stored at physical chunk lc^(row&7), half (l&1)
            *(ushort4*)&As[row * 256 + (((l >> 1) ^ (row & 7)) << 3) + ((l & 1) << 2)] = ov;
        }
    }
    __syncthreads();   // out-tile complete

    // ---- PD GEMM phase: 8 waves x 2 N-tiles, K=256 ----
    f32x4 acc[4][2];
#pragma unroll
    for (int mt = 0; mt < 4; ++mt)
#pragma unroll
        for (int nt = 0; nt < 2; ++nt) acc[mt][nt] = (f32x4){0.f, 0.f, 0.f, 0.f};

#pragma unroll
    for (int kt = 0; kt < 8; ++kt) {
        bf16x8 af[4];
#pragma unroll
        for (int mt = 0; mt < 4; ++mt) {
            int row  = mt * 16 + c;
            int slot = (kt * 4 + q) ^ (row & 7);
            af[mt] = *(const bf16x8*)&As[row * 256 + slot * 8];
        }
#pragma unroll
        for (int nt = 0; nt < 2; ++nt) {
            int ntg = w * 2 + nt;
            bf16x8 bv8 = *(const bf16x8*)&Wcp[(size_t)((kt * 16 + ntg) * 64 + l) * 8];
#pragma unroll
            for (int mt = 0; mt < 4; ++mt)
                acc[mt][nt] = __builtin_amdgcn_mfma_f32_16x16x32_bf16(af[mt], bv8, acc[mt][nt], 0, 0, 0);
        }
    }
    __syncthreads();   // all As reads done; slab regions alias As

    short* slab = &sh[w * PSLAB];   // [64][40], cols w*32..w*32+32
#pragma unroll
    for (int nt = 0; nt < 2; ++nt)
#pragma unroll
        for (int mt = 0; mt < 4; ++mt)
#pragma unroll
            for (int r = 0; r < 4; ++r)
                slab[(mt * 16 + q * 4 + r) * 40 + nt * 16 + c] =
                    (short)fbf(acc[mt][nt][r]);
    __syncthreads();   // slabs visible cross-wave

    // store: wave w stores rows w*8..w*8+8; lane l -> col-chunk cc=l&31 (8 cols)
    const int cc = l & 31;
    const short* sb = &sh[(cc >> 2) * PSLAB + (cc & 3) * 8];
#pragma unroll
    for (int i = 0; i < 4; ++i) {
        int row = w * 8 + i * 2 + (l >> 5);
        int gr  = m0 + row;
        if (gr < N_NODES)
            *(bf16x8*)&PD[(size_t)gr * HD + cc * 8] = *(const bf16x8*)&sb[row * 40];
    }
}

// ---------- K5: light edge MLP — h1 = relu(P[src]+D[dst]+b1); layer2 MFMA; layer3 ----------
__global__ __launch_bounds__(256) void edge_mlp_pd(
    const int* __restrict__ csr_src, const int* __restrict__ csr_dst,
    const int* __restrict__ csr_eid,
    const unsigned short* __restrict__ PD,
    const float* __restrict__ b1,
    const unsigned short* __restrict__ W2p, const float* __restrict__ b2,
    const float* __restrict__ W3, const float* __restrict__ b3,
    float* __restrict__ rating)
{
    __shared__ __align__(16) char lds[64 * 136 * 2];   // 17408 B union:
    short* h1t = (short*)lds;                          //   h1 bf16 [64][136]
    float* h2s = (float*)lds;                          //   h2 f32 [64][65] (aliases after barrier)

    const int t = threadIdx.x;
    const int w = t >> 6, l = t & 63;
    const int q = l >> 4, c = l & 15;
    const int e0 = blockIdx.x * 64;

    // stage h1 = relu(P[src] + D[dst] + b1): 64 rows x 128 cols bf16
#pragma unroll
    for (int j = 0; j < 4; ++j) {
        int idx = t + j * 256;          // 1024 chunks of 8 elems
        int row = idx >> 4, ch = idx & 15;
        int src = csr_src[e0 + row];
        int dst = csr_dst[e0 + row];
        bf16x8 pv = *(const bf16x8*)&PD[(size_t)src * HD + ch * 8];
        bf16x8 dv = *(const bf16x8*)&PD[(size_t)dst * HD + 128 + ch * 8];
        float4 ba = *(const float4*)&b1[ch * 8];
        float4 bb = *(const float4*)&b1[ch * 8 + 4];
        bf16x8 hv;
        hv[0] = (short)fbf(fmaxf(bf2f((unsigned short)pv[0]) + bf2f((unsigned short)dv[0]) + ba.x, 0.f));
        hv[1] = (short)fbf(fmaxf(bf2f((unsigned short)pv[1]) + bf2f((unsigned short)dv[1]) + ba.y, 0.f));
        hv[2] = (short)fbf(fmaxf(bf2f((unsigned short)pv[2]) + bf2f((unsigned short)dv[2]) + ba.z, 0.f));
        hv[3] = (short)fbf(fmaxf(bf2f((unsigned short)pv[3]) + bf2f((unsigned short)dv[3]) + ba.w, 0.f));
        hv[4] = (short)fbf(fmaxf(bf2f((unsigned short)pv[4]) + bf2f((unsigned short)dv[4]) + bb.x, 0.f));
        hv[5] = (short)fbf(fmaxf(bf2f((unsigned short)pv[5]) + bf2f((unsigned short)dv[5]) + bb.y, 0.f));
        hv[6] = (short)fbf(fmaxf(bf2f((unsigned short)pv[6]) + bf2f((unsigned short)dv[6]) + bb.z, 0.f));
        hv[7] = (short)fbf(fmaxf(bf2f((unsigned short)pv[7]) + bf2f((unsigned short)dv[7]) + bb.w, 0.f));
        *(bf16x8*)&h1t[row * 136 + ch * 8] = hv;
    }
    __syncthreads();

    // layer2 MFMA: [64,128] @ [128,64]
    f32x4 acc2[4];
#pragma unroll
    for (int i = 0; i < 4; ++i) acc2[i] = (f32x4){0.f, 0.f, 0.f, 0.f};
#pragma unroll
    for (int kt = 0; kt < 4; ++kt) {
        bf16x8 av = *(const bf16x8*)&h1t[(w * 16 + c) * 136 + kt * 32 + q * 8];
#pragma unroll
        for (int nt = 0; nt < 4; ++nt) {
            bf16x8 bv = *(const bf16x8*)&W2p[(size_t)((kt * 4 + nt) * 64 + l) * 8];
            acc2[nt] = __builtin_amdgcn_mfma_f32_16x16x32_bf16(av, bv, acc2[nt], 0, 0, 0);
        }
    }
    __syncthreads();   // h1 reads done; h2 aliases

#pragma unroll
    for (int nt = 0; nt < 4; ++nt) {
        float bv = b2[nt * 16 + c];
#pragma unroll
        for (int r = 0; r < 4; ++r)
            h2s[(w * 16 + q * 4 + r) * 65 + nt * 16 + c] = fmaxf(acc2[nt][r] + bv, 0.f);
    }
    __syncthreads();

    // layer3: all 256 threads — 4 partials per edge + shfl reduce
    {
        int e = t >> 2, part = t & 3;
        float a = 0.f;
#pragma unroll
        for (int kk = 0; kk < 16; ++kk)
            a += h2s[e * 65 + part * 16 + kk] * W3[part * 16 + kk];
        a += __shfl_xor(a, 1);
        a += __shfl_xor(a, 2);
        if (part == 0)
            rating[csr_eid[e0 + e]] = 4.f / (1.f + __expf(-(a + b3[0]))) + 1.f;
    }
}

extern "C" void kernel_launch(void* const* d_in, const int* in_sizes, int n_in,
                              void* d_out, int out_size, void* d_ws, size_t ws_size,
                              hipStream_t stream) {
    const int*   ei  = (const int*)d_in[0];    // [2, E]
    const float* x   = (const float*)d_in[2];
    const float* mem = (const float*)d_in[3];
    const float* Wq  = (const float*)d_in[4];
    const float* bq  = (const float*)d_in[5];
    const float* Wk  = (const float*)d_in[6];
    const float* bk  = (const float*)d_in[7];
    const float* Wv  = (const float*)d_in[8];
    const float* bv  = (const float*)d_in[9];
    const float* Ws  = (const float*)d_in[10];
    const float* bs  = (const float*)d_in[11];
    const float* W1  = (const float*)d_in[12];
    const float* b1  = (const float*)d_in[13];
    const float* W2  = (const float*)d_in[14];
    const float* b2  = (const float*)d_in[15];
    const float* W3  = (const float*)d_in[16];
    const float* b3  = (const float*)d_in[17];
    float* rating = (float*)d_out;

    // Workspace (~237 MB):
    //   Q  [N,256] bf16 (PD aliases Q after attn_pd)          51.2 MB
    //   KV [N,512] bf16 (lane-interleaved K|V)               102.4 MB
    //   S  [N,256] bf16                                       51.2 MB
    //   H  [N,128] bf16 (x+mem)                               25.6 MB
    //   rp, deg, cursor, csr_*, bsum, packs                   ~6.8 MB
    unsigned short* Q = (unsigned short*)d_ws;
    const size_t NHDe = (size_t)N_NODES * HD;   // 25.6M elements
    unsigned short* KV = Q + NHDe;              // N*512 elements
    unsigned short* S  = KV + 2 * NHDe;
    unsigned short* H  = S + NHDe;              // N*128 elements
    int* rp      = (int*)(H + (size_t)N_NODES * HID);
    int* deg     = rp + N_NODES;
    int* cursor  = deg + N_NODES;
    int* csr_src = cursor + N_NODES;
    int* csr_dst = csr_src + N_EDGES;
    int* csr_eid = csr_dst + N_EDGES;
    int* bsum    = csr_eid + N_EDGES;
    unsigned short* Wp  = (unsigned short*)(bsum + 128);
    unsigned short* Wcp = Wp + 16384 * 8;
    unsigned short* W2p = Wcp + 8192 * 8;
    unsigned short* PD  = Q;   // attn_pd writes PD in place of Q (row-owner-only)

    const int eblk  = (N_EDGES + 255) / 256;
    const int pblk  = (N_NODES * HID / 8 + 255) / 256;   // 6250
    const int gblk  = (N_NODES + 63) / 64;               // 1563

    // CSR build + weight packing (deg and cursor are adjacent -> one memset)
    hipMemsetAsync(deg, 0, sizeof(int) * 2 * N_NODES, stream);
    k_deg<<<eblk, 256, 0, stream>>>(ei, deg);
    k_scan1<<<NB_SCAN, 256, 0, stream>>>(deg, rp, bsum);
    k_scan2<<<1, 256, 0, stream>>>(bsum);
    k_bucket<<<eblk, 256, 0, stream>>>(ei, rp, bsum, cursor, csr_src, csr_dst, csr_eid);
    pack_all<<<100, 256, 0, stream>>>(Wq, Wk, Wv, Ws, W1, W2, Wp, Wcp, W2p);

    // H = bf16(x + mem), one streaming pass
    k_pre<<<pblk, 256, 0, stream>>>(x, mem, H);

    // projections: y=0 -> Q,S ; y=1 -> K,V (merged interleaved store); half-slab
    gemm4<<<dim3(gblk, 2), dim3(256), 0, stream>>>(
        H, Wp, bq, bk, bv, bs, Q, KV, S);

    // fused attention + PD GEMM (serial ladder; PD overwrites Q)
    attn_pd<<<gblk, 512, 0, stream>>>(rp, bsum, deg, csr_src, Q, KV, S, Wcp, PD);

    // light edge MLP in CSR order
    edge_mlp_pd<<<N_EDGES / 64, 256, 0, stream>>>(
        csr_src, csr_dst, csr_eid, PD, b1, W2p, b2, W3, b3, rating);
}